// Round 1
// baseline (7449.897 us; speedup 1.0000x reference)
//
#include <hip/hip_runtime.h>
#include <math.h>

#define DMODEL 768
#define NHEAD 12
#define DHEAD 64
#define HIDDEN 3072
#define NLAYER 6
#define SEQ 1024

// ---------------------------------------------------------------- reductions
__device__ __forceinline__ float block_sum(float v, float* red) {
    int tid = threadIdx.x;
    red[tid] = v;
    __syncthreads();
#pragma unroll
    for (int s = 128; s > 0; s >>= 1) {
        if (tid < s) red[tid] += red[tid + s];
        __syncthreads();
    }
    float r = red[0];
    __syncthreads();
    return r;
}

__device__ __forceinline__ float block_max(float v, float* red) {
    int tid = threadIdx.x;
    red[tid] = v;
    __syncthreads();
#pragma unroll
    for (int s = 128; s > 0; s >>= 1) {
        if (tid < s) red[tid] = fmaxf(red[tid], red[tid + s]);
        __syncthreads();
    }
    float r = red[0];
    __syncthreads();
    return r;
}

// ---------------------------------------------------------------- elementwise
__global__ __launch_bounds__(256) void add_kernel(const float* __restrict__ a,
                                                  const float* __restrict__ b,
                                                  float* __restrict__ o, int n) {
    int i = blockIdx.x * 256 + threadIdx.x;
    if (i < n) o[i] = a[i] + b[i];
}

// ---------------------------------------------------------------- GEMM: C = alpha*A*B^T (+bias) (+relu) (+causal mask)
// A: [N x K] row-major (lda), B: [M x K] row-major (ldb), C: [N x M] (ldc)
// blockIdx.z batching via element offsets Aoff/Boff/Coff.
// Tile 64x64, BK=32, 256 threads, 4x4 per thread.
__global__ __launch_bounds__(256) void gemm_nt(
    const float* __restrict__ A, int lda, long long Aoff,
    const float* __restrict__ B, int ldb, long long Boff,
    const float* __restrict__ bias,
    float* __restrict__ C, int ldc, long long Coff,
    int K, float alpha, int relu, int causal)
{
    A += (long long)blockIdx.z * Aoff;
    B += (long long)blockIdx.z * Boff;
    C += (long long)blockIdx.z * Coff;

    __shared__ float As[32][68];  // k-major, +4 pad keeps float4 alignment, 2-way banks
    __shared__ float Bs[32][68];

    const int tid = threadIdx.x;
    const int tx = tid & 15, ty = tid >> 4;
    const int n0 = blockIdx.y * 64, m0 = blockIdx.x * 64;

    float acc[4][4] = {};

    for (int k0 = 0; k0 < K; k0 += 32) {
#pragma unroll
        for (int t = 0; t < 2; ++t) {
            int p = tid + t * 256;        // 0..511
            int r = p >> 3;               // 0..63
            int ku = (p & 7) << 2;        // 0,4,...,28
            float4 a4 = *(const float4*)(A + (long long)(n0 + r) * lda + k0 + ku);
            As[ku + 0][r] = a4.x; As[ku + 1][r] = a4.y;
            As[ku + 2][r] = a4.z; As[ku + 3][r] = a4.w;
            float4 b4 = *(const float4*)(B + (long long)(m0 + r) * ldb + k0 + ku);
            Bs[ku + 0][r] = b4.x; Bs[ku + 1][r] = b4.y;
            Bs[ku + 2][r] = b4.z; Bs[ku + 3][r] = b4.w;
        }
        __syncthreads();
#pragma unroll
        for (int kq = 0; kq < 32; ++kq) {
            float a_[4], b_[4];
            *(float4*)a_ = *(const float4*)&As[kq][ty << 2];
            *(float4*)b_ = *(const float4*)&Bs[kq][tx << 2];
#pragma unroll
            for (int i = 0; i < 4; ++i)
#pragma unroll
                for (int j = 0; j < 4; ++j)
                    acc[i][j] = fmaf(a_[i], b_[j], acc[i][j]);
        }
        __syncthreads();
    }

#pragma unroll
    for (int i = 0; i < 4; ++i) {
        int row = n0 + (ty << 2) + i;
#pragma unroll
        for (int j = 0; j < 4; ++j) {
            int col = m0 + (tx << 2) + j;
            float v = acc[i][j] * alpha;
            if (bias) v += bias[col];
            if (relu) v = fmaxf(v, 0.0f);
            if (causal && col > row) v -= 10000.0f;
            C[(long long)row * ldc + col] = v;
        }
    }
}

// ---------------------------------------------------------------- GEMM: C = A*B  (B is [K x M] row-major)
__global__ __launch_bounds__(256) void gemm_nn(
    const float* __restrict__ A, int lda, long long Aoff,
    const float* __restrict__ B, int ldb, long long Boff,
    float* __restrict__ C, int ldc, long long Coff,
    int K)
{
    A += (long long)blockIdx.z * Aoff;
    B += (long long)blockIdx.z * Boff;
    C += (long long)blockIdx.z * Coff;

    __shared__ float As[32][68];
    __shared__ float Bs[32][68];

    const int tid = threadIdx.x;
    const int tx = tid & 15, ty = tid >> 4;
    const int n0 = blockIdx.y * 64, m0 = blockIdx.x * 64;

    float acc[4][4] = {};

    for (int k0 = 0; k0 < K; k0 += 32) {
#pragma unroll
        for (int t = 0; t < 2; ++t) {
            int p = tid + t * 256;
            int r = p >> 3;
            int ku = (p & 7) << 2;
            float4 a4 = *(const float4*)(A + (long long)(n0 + r) * lda + k0 + ku);
            As[ku + 0][r] = a4.x; As[ku + 1][r] = a4.y;
            As[ku + 2][r] = a4.z; As[ku + 3][r] = a4.w;
            // B tile: rows k0..k0+31, cols m0..m0+63
            int kb = p >> 4;              // 0..31
            int cu = (p & 15) << 2;       // 0..60
            *(float4*)&Bs[kb][cu] = *(const float4*)(B + (long long)(k0 + kb) * ldb + m0 + cu);
        }
        __syncthreads();
#pragma unroll
        for (int kq = 0; kq < 32; ++kq) {
            float a_[4], b_[4];
            *(float4*)a_ = *(const float4*)&As[kq][ty << 2];
            *(float4*)b_ = *(const float4*)&Bs[kq][tx << 2];
#pragma unroll
            for (int i = 0; i < 4; ++i)
#pragma unroll
                for (int j = 0; j < 4; ++j)
                    acc[i][j] = fmaf(a_[i], b_[j], acc[i][j]);
        }
        __syncthreads();
    }

#pragma unroll
    for (int i = 0; i < 4; ++i) {
        int row = n0 + (ty << 2) + i;
#pragma unroll
        for (int j = 0; j < 4; ++j) {
            int col = m0 + (tx << 2) + j;
            C[(long long)row * ldc + col] = acc[i][j];
        }
    }
}

// ---------------------------------------------------------------- row softmax (width multiple of 4, <=1024)
__global__ __launch_bounds__(256) void softmax_kernel(const float* __restrict__ in,
                                                      float* __restrict__ out, int width) {
    const float* row = in + (long long)blockIdx.x * width;
    float* orow = out + (long long)blockIdx.x * width;
    int tid = threadIdx.x;
    __shared__ float red[256];
    int nf4 = width >> 2;

    float4 v = {-1e30f, -1e30f, -1e30f, -1e30f};
    if (tid < nf4) v = ((const float4*)row)[tid];
    float mx = fmaxf(fmaxf(v.x, v.y), fmaxf(v.z, v.w));
    mx = block_max(mx, red);

    float4 e = {0.f, 0.f, 0.f, 0.f};
    float s = 0.f;
    if (tid < nf4) {
        e.x = __expf(v.x - mx); e.y = __expf(v.y - mx);
        e.z = __expf(v.z - mx); e.w = __expf(v.w - mx);
        s = e.x + e.y + e.z + e.w;
    }
    s = block_sum(s, red);
    float inv = 1.0f / s;
    if (tid < nf4) {
        e.x *= inv; e.y *= inv; e.z *= inv; e.w *= inv;
        ((float4*)orow)[tid] = e;
    }
}

// ---------------------------------------------------------------- x = LN(x + fx), unbiased std, eps added to std
__global__ __launch_bounds__(256) void ln_res_kernel(float* __restrict__ x,
                                                     const float* __restrict__ fx,
                                                     const float* __restrict__ ga,
                                                     const float* __restrict__ gb) {
    long long row = blockIdx.x;
    float* xr = x + row * DMODEL;
    const float* fr = fx + row * DMODEL;
    int tid = threadIdx.x;
    __shared__ float red[256];

    float4 t = {0.f, 0.f, 0.f, 0.f};
    if (tid < 192) {
        float4 a = ((const float4*)xr)[tid];
        float4 f = ((const float4*)fr)[tid];
        t.x = a.x + f.x; t.y = a.y + f.y; t.z = a.z + f.z; t.w = a.w + f.w;
    }
    float sum = t.x + t.y + t.z + t.w;
    sum = block_sum(sum, red);
    float mean = sum * (1.0f / (float)DMODEL);

    float4 d = {0.f, 0.f, 0.f, 0.f};
    float ss = 0.f;
    if (tid < 192) {
        d.x = t.x - mean; d.y = t.y - mean; d.z = t.z - mean; d.w = t.w - mean;
        ss = d.x * d.x + d.y * d.y + d.z * d.z + d.w * d.w;
    }
    ss = block_sum(ss, red);
    float stdv = sqrtf(ss / (float)(DMODEL - 1));
    float inv = 1.0f / (stdv + 1e-6f);

    if (tid < 192) {
        float4 A = ((const float4*)ga)[tid];
        float4 B = ((const float4*)gb)[tid];
        float4 o;
        o.x = A.x * d.x * inv + B.x;
        o.y = A.y * d.y * inv + B.y;
        o.z = A.z * d.z * inv + B.z;
        o.w = A.w * d.w * inv + B.w;
        ((float4*)xr)[tid] = o;
    }
}

// ---------------------------------------------------------------- host helpers
static inline void launch_gemm_nt(hipStream_t st,
                                  const float* A, int lda, long long Aoff,
                                  const float* B, int ldb, long long Boff,
                                  const float* bias,
                                  float* C, int ldc, long long Coff,
                                  int N, int M, int K, float alpha, int relu, int causal, int batch) {
    dim3 grid(M / 64, N / 64, batch);
    hipLaunchKernelGGL(gemm_nt, grid, dim3(256), 0, st,
                       A, lda, Aoff, B, ldb, Boff, bias, C, ldc, Coff, K, alpha, relu, causal);
}

static inline void launch_gemm_nn(hipStream_t st,
                                  const float* A, int lda, long long Aoff,
                                  const float* B, int ldb, long long Boff,
                                  float* C, int ldc, long long Coff,
                                  int N, int M, int K, int batch) {
    dim3 grid(M / 64, N / 64, batch);
    hipLaunchKernelGGL(gemm_nn, grid, dim3(256), 0, st,
                       A, lda, Aoff, B, ldb, Boff, C, ldc, Coff, K);
}

extern "C" void kernel_launch(void* const* d_in, const int* in_sizes, int n_in,
                              void* d_out, int out_size, void* d_ws, size_t ws_size,
                              hipStream_t stream) {
    const float* xl      = (const float*)d_in[0];
    const float* dl      = (const float*)d_in[1];
    const float* pe      = (const float*)d_in[2];
    const float* enc_wq  = (const float*)d_in[3];
    const float* enc_wk  = (const float*)d_in[4];
    const float* enc_wv  = (const float*)d_in[5];
    const float* enc_wo  = (const float*)d_in[6];
    const float* enc_bo  = (const float*)d_in[7];
    const float* enc_lna = (const float*)d_in[8];
    const float* enc_lnb = (const float*)d_in[9];
    const float* enc_w1  = (const float*)d_in[10];
    const float* enc_b1  = (const float*)d_in[11];
    const float* enc_w2  = (const float*)d_in[12];
    const float* enc_b2  = (const float*)d_in[13];
    const float* dec_wq  = (const float*)d_in[14];
    const float* dec_wk  = (const float*)d_in[15];
    const float* dec_wv  = (const float*)d_in[16];
    const float* dec_wo  = (const float*)d_in[17];
    const float* dec_bo  = (const float*)d_in[18];
    const float* dec_cwq = (const float*)d_in[19];
    const float* dec_cwk = (const float*)d_in[20];
    const float* dec_cwv = (const float*)d_in[21];
    const float* dec_cwo = (const float*)d_in[22];
    const float* dec_cbo = (const float*)d_in[23];
    const float* dec_lna = (const float*)d_in[24];
    const float* dec_lnb = (const float*)d_in[25];
    const float* dec_w1  = (const float*)d_in[26];
    const float* dec_b1  = (const float*)d_in[27];
    const float* dec_w2  = (const float*)d_in[28];
    const float* dec_b2  = (const float*)d_in[29];

    const long long AC = (long long)SEQ * DMODEL;          // 786432
    const long long SS = (long long)SEQ * SEQ;             // 1048576
    const long long DD = (long long)DMODEL * DMODEL;       // 589824
    const long long WH = (long long)HIDDEN * DMODEL;       // 2359296

    float* ws   = (float*)d_ws;
    float* mbuf = ws;                                      // encoder stream
    float* xbuf = mbuf + AC;                               // decoder stream
    float* qbuf = xbuf + AC;
    float* kbuf = qbuf + AC;
    float* vbuf = kbuf + AC;
    float* abuf = vbuf + AC;                               // attention concat out
    float* fbuf = abuf + AC;                               // sublayer output
    float* hbuf = fbuf + AC;                               // ffn hidden [SEQ x HIDDEN]
    float* sbuf = hbuf + (long long)SEQ * HIDDEN;          // scores [H x SEQ x SEQ]

    // m = xl + pos_enc
    hipLaunchKernelGGL(add_kernel, dim3((int)(AC / 256)), dim3(256), 0, stream, xl, pe, mbuf, (int)AC);

    // ---------------- encoder ----------------
    for (int l = 0; l < NLAYER; ++l) {
        const float* wq = enc_wq + (long long)l * DD;
        const float* wk = enc_wk + (long long)l * DD;
        const float* wv = enc_wv + (long long)l * DD;
        const float* wo = enc_wo + (long long)l * DD;
        const float* bo = enc_bo + (long long)l * DMODEL;

        launch_gemm_nt(stream, mbuf, DMODEL, 0, wq, DMODEL, 0, nullptr, qbuf, DMODEL, 0,
                       SEQ, DMODEL, DMODEL, 1.0f, 0, 0, 1);
        launch_gemm_nt(stream, mbuf, DMODEL, 0, wk, DMODEL, 0, nullptr, kbuf, DMODEL, 0,
                       SEQ, DMODEL, DMODEL, 1.0f, 0, 0, 1);
        launch_gemm_nt(stream, mbuf, DMODEL, 0, wv, DMODEL, 0, nullptr, vbuf, DMODEL, 0,
                       SEQ, DMODEL, DMODEL, 1.0f, 0, 0, 1);
        // scores = Q K^T / 8  (batched over heads)
        launch_gemm_nt(stream, qbuf, DMODEL, DHEAD, kbuf, DMODEL, DHEAD, nullptr, sbuf, SEQ, SS,
                       SEQ, SEQ, DHEAD, 0.125f, 0, 0, NHEAD);
        hipLaunchKernelGGL(softmax_kernel, dim3(NHEAD * SEQ), dim3(256), 0, stream, sbuf, sbuf, SEQ);
        // O = P V
        launch_gemm_nn(stream, sbuf, SEQ, SS, vbuf, DMODEL, DHEAD, abuf, DMODEL, DHEAD,
                       SEQ, DHEAD, SEQ, NHEAD);
        launch_gemm_nt(stream, abuf, DMODEL, 0, wo, DMODEL, 0, bo, fbuf, DMODEL, 0,
                       SEQ, DMODEL, DMODEL, 1.0f, 0, 0, 1);
        hipLaunchKernelGGL(ln_res_kernel, dim3(SEQ), dim3(256), 0, stream,
                           mbuf, fbuf, enc_lna + (long long)(l * 2 + 0) * DMODEL, enc_lnb + (long long)(l * 2 + 0) * DMODEL);
        // FFN
        launch_gemm_nt(stream, mbuf, DMODEL, 0, enc_w1 + (long long)l * WH, DMODEL, 0,
                       enc_b1 + (long long)l * HIDDEN, hbuf, HIDDEN, 0,
                       SEQ, HIDDEN, DMODEL, 1.0f, 1, 0, 1);
        launch_gemm_nt(stream, hbuf, HIDDEN, 0, enc_w2 + (long long)l * WH, HIDDEN, 0,
                       enc_b2 + (long long)l * DMODEL, fbuf, DMODEL, 0,
                       SEQ, DMODEL, HIDDEN, 1.0f, 0, 0, 1);
        hipLaunchKernelGGL(ln_res_kernel, dim3(SEQ), dim3(256), 0, stream,
                           mbuf, fbuf, enc_lna + (long long)(l * 2 + 1) * DMODEL, enc_lnb + (long long)(l * 2 + 1) * DMODEL);
    }

    // out = dl + pos_enc
    hipLaunchKernelGGL(add_kernel, dim3((int)(AC / 256)), dim3(256), 0, stream, dl, pe, xbuf, (int)AC);

    // ---------------- decoder ----------------
    for (int l = 0; l < NLAYER; ++l) {
        // --- self attention (causal) ---
        launch_gemm_nt(stream, xbuf, DMODEL, 0, dec_wq + (long long)l * DD, DMODEL, 0, nullptr, qbuf, DMODEL, 0,
                       SEQ, DMODEL, DMODEL, 1.0f, 0, 0, 1);
        launch_gemm_nt(stream, xbuf, DMODEL, 0, dec_wk + (long long)l * DD, DMODEL, 0, nullptr, kbuf, DMODEL, 0,
                       SEQ, DMODEL, DMODEL, 1.0f, 0, 0, 1);
        launch_gemm_nt(stream, xbuf, DMODEL, 0, dec_wv + (long long)l * DD, DMODEL, 0, nullptr, vbuf, DMODEL, 0,
                       SEQ, DMODEL, DMODEL, 1.0f, 0, 0, 1);
        launch_gemm_nt(stream, qbuf, DMODEL, DHEAD, kbuf, DMODEL, DHEAD, nullptr, sbuf, SEQ, SS,
                       SEQ, SEQ, DHEAD, 0.125f, 0, 1 /*causal*/, NHEAD);
        hipLaunchKernelGGL(softmax_kernel, dim3(NHEAD * SEQ), dim3(256), 0, stream, sbuf, sbuf, SEQ);
        launch_gemm_nn(stream, sbuf, SEQ, SS, vbuf, DMODEL, DHEAD, abuf, DMODEL, DHEAD,
                       SEQ, DHEAD, SEQ, NHEAD);
        launch_gemm_nt(stream, abuf, DMODEL, 0, dec_wo + (long long)l * DD, DMODEL, 0,
                       dec_bo + (long long)l * DMODEL, fbuf, DMODEL, 0,
                       SEQ, DMODEL, DMODEL, 1.0f, 0, 0, 1);
        hipLaunchKernelGGL(ln_res_kernel, dim3(SEQ), dim3(256), 0, stream,
                           xbuf, fbuf, dec_lna + (long long)(l * 3 + 0) * DMODEL, dec_lnb + (long long)(l * 3 + 0) * DMODEL);

        // --- cross attention (Q from decoder, K/V from encoder memory) ---
        launch_gemm_nt(stream, xbuf, DMODEL, 0, dec_cwq + (long long)l * DD, DMODEL, 0, nullptr, qbuf, DMODEL, 0,
                       SEQ, DMODEL, DMODEL, 1.0f, 0, 0, 1);
        launch_gemm_nt(stream, mbuf, DMODEL, 0, dec_cwk + (long long)l * DD, DMODEL, 0, nullptr, kbuf, DMODEL, 0,
                       SEQ, DMODEL, DMODEL, 1.0f, 0, 0, 1);
        launch_gemm_nt(stream, mbuf, DMODEL, 0, dec_cwv + (long long)l * DD, DMODEL, 0, nullptr, vbuf, DMODEL, 0,
                       SEQ, DMODEL, DMODEL, 1.0f, 0, 0, 1);
        launch_gemm_nt(stream, qbuf, DMODEL, DHEAD, kbuf, DMODEL, DHEAD, nullptr, sbuf, SEQ, SS,
                       SEQ, SEQ, DHEAD, 0.125f, 0, 0, NHEAD);
        hipLaunchKernelGGL(softmax_kernel, dim3(NHEAD * SEQ), dim3(256), 0, stream, sbuf, sbuf, SEQ);
        launch_gemm_nn(stream, sbuf, SEQ, SS, vbuf, DMODEL, DHEAD, abuf, DMODEL, DHEAD,
                       SEQ, DHEAD, SEQ, NHEAD);
        launch_gemm_nt(stream, abuf, DMODEL, 0, dec_cwo + (long long)l * DD, DMODEL, 0,
                       dec_cbo + (long long)l * DMODEL, fbuf, DMODEL, 0,
                       SEQ, DMODEL, DMODEL, 1.0f, 0, 0, 1);
        hipLaunchKernelGGL(ln_res_kernel, dim3(SEQ), dim3(256), 0, stream,
                           xbuf, fbuf, dec_lna + (long long)(l * 3 + 1) * DMODEL, dec_lnb + (long long)(l * 3 + 1) * DMODEL);

        // --- FFN ---
        launch_gemm_nt(stream, xbuf, DMODEL, 0, dec_w1 + (long long)l * WH, DMODEL, 0,
                       dec_b1 + (long long)l * HIDDEN, hbuf, HIDDEN, 0,
                       SEQ, HIDDEN, DMODEL, 1.0f, 1, 0, 1);
        launch_gemm_nt(stream, hbuf, HIDDEN, 0, dec_w2 + (long long)l * WH, HIDDEN, 0,
                       dec_b2 + (long long)l * DMODEL, fbuf, DMODEL, 0,
                       SEQ, DMODEL, HIDDEN, 1.0f, 0, 0, 1);
        hipLaunchKernelGGL(ln_res_kernel, dim3(SEQ), dim3(256), 0, stream,
                           xbuf, fbuf, dec_lna + (long long)(l * 3 + 2) * DMODEL, dec_lnb + (long long)(l * 3 + 2) * DMODEL);
    }

    // final row softmax over features -> d_out
    hipLaunchKernelGGL(softmax_kernel, dim3(SEQ), dim3(256), 0, stream, xbuf, (float*)d_out, DMODEL);
}

// Round 2
// 3280.897 us; speedup vs baseline: 2.2707x; 2.2707x over previous
//
#include <hip/hip_runtime.h>
#include <math.h>

#define DMODEL 768
#define NHEAD 12
#define DHEAD 64
#define HIDDEN 3072
#define NLAYER 6
#define SEQ 1024

typedef unsigned short u16;
typedef __attribute__((ext_vector_type(8))) short short8;
typedef __attribute__((ext_vector_type(4))) float f32x4;

__device__ __forceinline__ u16 f2bf(float f) {
    union { float f; unsigned u; } v; v.f = f;
    unsigned u = v.u;
    return (u16)((u + 0x7fffu + ((u >> 16) & 1u)) >> 16);
}
__device__ __forceinline__ float bf2f(u16 b) {
    union { unsigned u; float f; } v; v.u = ((unsigned)b) << 16; return v.f;
}

// ---------------------------------------------------------------- reductions
__device__ __forceinline__ float block_sum(float v, float* red) {
    int tid = threadIdx.x;
    red[tid] = v;
    __syncthreads();
#pragma unroll
    for (int s = 128; s > 0; s >>= 1) {
        if (tid < s) red[tid] += red[tid + s];
        __syncthreads();
    }
    float r = red[0];
    __syncthreads();
    return r;
}
__device__ __forceinline__ float block_max(float v, float* red) {
    int tid = threadIdx.x;
    red[tid] = v;
    __syncthreads();
#pragma unroll
    for (int s = 128; s > 0; s >>= 1) {
        if (tid < s) red[tid] = fmaxf(red[tid], red[tid + s]);
        __syncthreads();
    }
    float r = red[0];
    __syncthreads();
    return r;
}

// ---------------------------------------------------------------- x+pe -> f32 + bf16
__global__ __launch_bounds__(256) void add_pe(const float* __restrict__ a,
                                              const float* __restrict__ b,
                                              float* __restrict__ o,
                                              u16* __restrict__ ob, int n) {
    int i = blockIdx.x * 256 + threadIdx.x;
    if (i < n) { float v = a[i] + b[i]; o[i] = v; ob[i] = f2bf(v); }
}

// ---------------------------------------------------------------- MFMA GEMM
// C[N x M] = alpha * A[N x K] * B[M x K]^T (+bias) (+relu) (+causal)
// A: bf16, row-major, k-contiguous. B: bf16 or fp32, row-major, k-contiguous.
// C: fp32 or bf16. Batch via blockIdx.z element offsets.
// Tile 64x64, BK=64, 256 threads = 4 waves of 32x32, XOR-swizzled LDS.
__global__ __launch_bounds__(256) void gemm_bf16(
    const u16* __restrict__ A, int lda, long long Aoff,
    const void* __restrict__ Bp, int ldb, long long Boff, int b_f32,
    const float* __restrict__ bias,
    void* __restrict__ Cp, int ldc, long long Coff, int c_bf16,
    int K, float alpha, int relu, int causal)
{
    __shared__ __align__(16) u16 As[64 * 64];
    __shared__ __align__(16) u16 Bs[64 * 64];

    A += (long long)blockIdx.z * Aoff;
    const u16*  B16 = (const u16*)Bp  + (long long)blockIdx.z * Boff;
    const float* B32 = (const float*)Bp + (long long)blockIdx.z * Boff;
    u16*   C16 = (u16*)Cp   + (long long)blockIdx.z * Coff;
    float* C32 = (float*)Cp + (long long)blockIdx.z * Coff;

    const int tid  = threadIdx.x;
    const int lane = tid & 63;
    const int wid  = tid >> 6;
    const int wr   = (wid >> 1) * 32;     // wave A-row offset
    const int wc   = (wid & 1) * 32;      // wave B-row (C-col) offset
    const int n0   = blockIdx.y * 64;     // A rows (output rows)
    const int m0   = blockIdx.x * 64;     // B rows (output cols)

    const int r0 = tid >> 3;              // staging rows r0, r0+32
    const int k8 = (tid & 7) << 3;        // staging k offset

    f32x4 acc[2][2] = {};

    for (int k0 = 0; k0 < K; k0 += 64) {
        // stage A (bf16)
#pragma unroll
        for (int i = 0; i < 2; ++i) {
            int row = r0 + i * 32;
            uint4 raw = *(const uint4*)(A + (long long)(n0 + row) * lda + k0 + k8);
            int e = (row << 6) + k8; e ^= (row & 7) << 3;
            *(uint4*)&As[e] = raw;
        }
        // stage B (bf16 passthrough or fp32 -> bf16)
        if (b_f32) {
#pragma unroll
            for (int i = 0; i < 2; ++i) {
                int row = r0 + i * 32;
                const float* s = B32 + (long long)(m0 + row) * ldb + k0 + k8;
                float4 x = *(const float4*)s;
                float4 y = *(const float4*)(s + 4);
                unsigned p0 = (unsigned)f2bf(x.x) | ((unsigned)f2bf(x.y) << 16);
                unsigned p1 = (unsigned)f2bf(x.z) | ((unsigned)f2bf(x.w) << 16);
                unsigned p2 = (unsigned)f2bf(y.x) | ((unsigned)f2bf(y.y) << 16);
                unsigned p3 = (unsigned)f2bf(y.z) | ((unsigned)f2bf(y.w) << 16);
                uint4 w = {p0, p1, p2, p3};
                int e = (row << 6) + k8; e ^= (row & 7) << 3;
                *(uint4*)&Bs[e] = w;
            }
        } else {
#pragma unroll
            for (int i = 0; i < 2; ++i) {
                int row = r0 + i * 32;
                uint4 raw = *(const uint4*)(B16 + (long long)(m0 + row) * ldb + k0 + k8);
                int e = (row << 6) + k8; e ^= (row & 7) << 3;
                *(uint4*)&Bs[e] = raw;
            }
        }
        __syncthreads();

        const int kl = (lane >> 4) << 3;   // 0,8,16,24
#pragma unroll
        for (int kk = 0; kk < 64; kk += 32) {
            short8 af[2], bfr[2];
#pragma unroll
            for (int m = 0; m < 2; ++m) {
                int row = wr + m * 16 + (lane & 15);
                int e = (row << 6) + kk + kl; e ^= (row & 7) << 3;
                af[m] = *(const short8*)&As[e];
            }
#pragma unroll
            for (int n = 0; n < 2; ++n) {
                int row = wc + n * 16 + (lane & 15);
                int e = (row << 6) + kk + kl; e ^= (row & 7) << 3;
                bfr[n] = *(const short8*)&Bs[e];
            }
#pragma unroll
            for (int m = 0; m < 2; ++m)
#pragma unroll
                for (int n = 0; n < 2; ++n)
                    acc[m][n] = __builtin_amdgcn_mfma_f32_16x16x32_bf16(af[m], bfr[n], acc[m][n], 0, 0, 0);
        }
        __syncthreads();
    }

    // epilogue: C/D layout col=lane&15 (B-dim), row=(lane>>4)*4+reg (A-dim)
    const int cj  = lane & 15;
    const int ci0 = (lane >> 4) << 2;
#pragma unroll
    for (int m = 0; m < 2; ++m) {
#pragma unroll
        for (int n = 0; n < 2; ++n) {
            int col = m0 + wc + n * 16 + cj;
            float bv = bias ? bias[col] : 0.0f;
#pragma unroll
            for (int r = 0; r < 4; ++r) {
                int row = n0 + wr + m * 16 + ci0 + r;
                float v = acc[m][n][r] * alpha + bv;
                if (relu) v = fmaxf(v, 0.0f);
                if (causal && col > row) v -= 10000.0f;
                if (c_bf16) C16[(long long)row * ldc + col] = f2bf(v);
                else        C32[(long long)row * ldc + col] = v;
            }
        }
    }
}

// ---------------------------------------------------------------- bf16 transpose [1024x768] -> [768x1024]
__global__ __launch_bounds__(256) void transpose_bf16(const u16* __restrict__ in,
                                                      u16* __restrict__ out) {
    __shared__ u16 T[64][72];
    int bi = blockIdx.x;   // input col block (0..11)
    int bj = blockIdx.y;   // input row block (0..15)
    int tid = threadIdx.x;
    int r = tid >> 3, c8 = (tid & 7) << 3;
#pragma unroll
    for (int i = 0; i < 2; ++i) {
        int row = r + i * 32;
        uint4 v = *(const uint4*)(in + (long long)(bj * 64 + row) * DMODEL + bi * 64 + c8);
        *(uint4*)&T[row][c8] = v;
    }
    __syncthreads();
#pragma unroll
    for (int i = 0; i < 2; ++i) {
        int row = r + i * 32;             // output row within tile = input col
        unsigned p0 = (unsigned)T[c8 + 0][row] | ((unsigned)T[c8 + 1][row] << 16);
        unsigned p1 = (unsigned)T[c8 + 2][row] | ((unsigned)T[c8 + 3][row] << 16);
        unsigned p2 = (unsigned)T[c8 + 4][row] | ((unsigned)T[c8 + 5][row] << 16);
        unsigned p3 = (unsigned)T[c8 + 6][row] | ((unsigned)T[c8 + 7][row] << 16);
        uint4 w = {p0, p1, p2, p3};
        *(uint4*)(out + (long long)(bi * 64 + row) * SEQ + bj * 64 + c8) = w;
    }
}

// ---------------------------------------------------------------- softmax over bf16 rows of 1024, in place
__global__ __launch_bounds__(256) void softmax_bf16(u16* __restrict__ p) {
    u16* row = p + (long long)blockIdx.x * SEQ;
    int tid = threadIdx.x;
    __shared__ float red[256];
    ushort4 r4 = ((const ushort4*)row)[tid];
    float x0 = bf2f(r4.x), x1 = bf2f(r4.y), x2 = bf2f(r4.z), x3 = bf2f(r4.w);
    float mx = fmaxf(fmaxf(x0, x1), fmaxf(x2, x3));
    mx = block_max(mx, red);
    float e0 = __expf(x0 - mx), e1 = __expf(x1 - mx), e2 = __expf(x2 - mx), e3 = __expf(x3 - mx);
    float s = e0 + e1 + e2 + e3;
    s = block_sum(s, red);
    float inv = 1.0f / s;
    ushort4 o;
    o.x = f2bf(e0 * inv); o.y = f2bf(e1 * inv); o.z = f2bf(e2 * inv); o.w = f2bf(e3 * inv);
    ((ushort4*)row)[tid] = o;
}

// ---------------------------------------------------------------- f32 row softmax (final, width<=1024, mult of 4)
__global__ __launch_bounds__(256) void softmax_f32(const float* __restrict__ in,
                                                   float* __restrict__ out, int width) {
    const float* row = in + (long long)blockIdx.x * width;
    float* orow = out + (long long)blockIdx.x * width;
    int tid = threadIdx.x;
    __shared__ float red[256];
    int nf4 = width >> 2;
    float4 v = {-1e30f, -1e30f, -1e30f, -1e30f};
    if (tid < nf4) v = ((const float4*)row)[tid];
    float mx = fmaxf(fmaxf(v.x, v.y), fmaxf(v.z, v.w));
    mx = block_max(mx, red);
    float4 e = {0.f, 0.f, 0.f, 0.f};
    float s = 0.f;
    if (tid < nf4) {
        e.x = __expf(v.x - mx); e.y = __expf(v.y - mx);
        e.z = __expf(v.z - mx); e.w = __expf(v.w - mx);
        s = e.x + e.y + e.z + e.w;
    }
    s = block_sum(s, red);
    float inv = 1.0f / s;
    if (tid < nf4) {
        e.x *= inv; e.y *= inv; e.z *= inv; e.w *= inv;
        ((float4*)orow)[tid] = e;
    }
}

// ---------------------------------------------------------------- x = LN(x + fx); also emit bf16 copy
__global__ __launch_bounds__(256) void ln_res_kernel(float* __restrict__ x,
                                                     const float* __restrict__ fx,
                                                     const float* __restrict__ ga,
                                                     const float* __restrict__ gb,
                                                     u16* __restrict__ xb) {
    long long row = blockIdx.x;
    float* xr = x + row * DMODEL;
    const float* fr = fx + row * DMODEL;
    u16* xbr = xb + row * DMODEL;
    int tid = threadIdx.x;
    __shared__ float red[256];

    float4 t = {0.f, 0.f, 0.f, 0.f};
    if (tid < 192) {
        float4 a = ((const float4*)xr)[tid];
        float4 f = ((const float4*)fr)[tid];
        t.x = a.x + f.x; t.y = a.y + f.y; t.z = a.z + f.z; t.w = a.w + f.w;
    }
    float sum = t.x + t.y + t.z + t.w;
    sum = block_sum(sum, red);
    float mean = sum * (1.0f / (float)DMODEL);

    float4 d = {0.f, 0.f, 0.f, 0.f};
    float ss = 0.f;
    if (tid < 192) {
        d.x = t.x - mean; d.y = t.y - mean; d.z = t.z - mean; d.w = t.w - mean;
        ss = d.x * d.x + d.y * d.y + d.z * d.z + d.w * d.w;
    }
    ss = block_sum(ss, red);
    float stdv = sqrtf(ss / (float)(DMODEL - 1));
    float inv = 1.0f / (stdv + 1e-6f);

    if (tid < 192) {
        float4 A = ((const float4*)ga)[tid];
        float4 B = ((const float4*)gb)[tid];
        float4 o;
        o.x = A.x * d.x * inv + B.x;
        o.y = A.y * d.y * inv + B.y;
        o.z = A.z * d.z * inv + B.z;
        o.w = A.w * d.w * inv + B.w;
        ((float4*)xr)[tid] = o;
        ushort4 ob;
        ob.x = f2bf(o.x); ob.y = f2bf(o.y); ob.z = f2bf(o.z); ob.w = f2bf(o.w);
        ((ushort4*)xbr)[tid] = ob;
    }
}

// ---------------------------------------------------------------- host side
static inline void g_launch(hipStream_t st,
                            const u16* A, int lda, long long Aoff,
                            const void* B, int ldb, long long Boff, int b_f32,
                            const float* bias,
                            void* C, int ldc, long long Coff, int c_bf16,
                            int N, int M, int K, float alpha, int relu, int causal, int batch) {
    dim3 grid(M / 64, N / 64, batch);
    hipLaunchKernelGGL(gemm_bf16, grid, dim3(256), 0, st,
                       A, lda, Aoff, B, ldb, Boff, b_f32, bias, C, ldc, Coff, c_bf16,
                       K, alpha, relu, causal);
}

extern "C" void kernel_launch(void* const* d_in, const int* in_sizes, int n_in,
                              void* d_out, int out_size, void* d_ws, size_t ws_size,
                              hipStream_t stream) {
    const float* xl      = (const float*)d_in[0];
    const float* dl      = (const float*)d_in[1];
    const float* pe      = (const float*)d_in[2];
    const float* enc_wq  = (const float*)d_in[3];
    const float* enc_wk  = (const float*)d_in[4];
    const float* enc_wv  = (const float*)d_in[5];
    const float* enc_wo  = (const float*)d_in[6];
    const float* enc_bo  = (const float*)d_in[7];
    const float* enc_lna = (const float*)d_in[8];
    const float* enc_lnb = (const float*)d_in[9];
    const float* enc_w1  = (const float*)d_in[10];
    const float* enc_b1  = (const float*)d_in[11];
    const float* enc_w2  = (const float*)d_in[12];
    const float* enc_b2  = (const float*)d_in[13];
    const float* dec_wq  = (const float*)d_in[14];
    const float* dec_wk  = (const float*)d_in[15];
    const float* dec_wv  = (const float*)d_in[16];
    const float* dec_wo  = (const float*)d_in[17];
    const float* dec_bo  = (const float*)d_in[18];
    const float* dec_cwq = (const float*)d_in[19];
    const float* dec_cwk = (const float*)d_in[20];
    const float* dec_cwv = (const float*)d_in[21];
    const float* dec_cwo = (const float*)d_in[22];
    const float* dec_cbo = (const float*)d_in[23];
    const float* dec_lna = (const float*)d_in[24];
    const float* dec_lnb = (const float*)d_in[25];
    const float* dec_w1  = (const float*)d_in[26];
    const float* dec_b1  = (const float*)d_in[27];
    const float* dec_w2  = (const float*)d_in[28];
    const float* dec_b2  = (const float*)d_in[29];

    const long long AC = (long long)SEQ * DMODEL;
    const long long SS = (long long)SEQ * SEQ;
    const long long DD = (long long)DMODEL * DMODEL;
    const long long WH = (long long)HIDDEN * DMODEL;

    float* f   = (float*)d_ws;
    float* mbuf = f;                // encoder stream (f32)
    float* xbuf = mbuf + AC;        // decoder stream (f32)
    float* fbuf = xbuf + AC;        // sublayer output (f32)
    u16* u = (u16*)(fbuf + AC);
    u16* mb16 = u;          u += AC;             // encoder stream bf16
    u16* xb16 = u;          u += AC;             // decoder stream bf16
    u16* qb   = u;          u += AC;
    u16* kb   = u;          u += AC;
    u16* vb   = u;          u += AC;
    u16* ob   = u;          u += AC;             // attention concat out
    u16* vt   = u;          u += AC;             // V^T [768][1024]
    u16* hb   = u;          u += (long long)SEQ * HIDDEN;  // ffn hidden bf16
    u16* pb   = u;          u += (long long)NHEAD * SS;    // scores/probs bf16

    hipLaunchKernelGGL(add_pe, dim3((int)(AC / 256)), dim3(256), 0, stream, xl, pe, mbuf, mb16, (int)AC);

    // ---------------- encoder ----------------
    for (int l = 0; l < NLAYER; ++l) {
        const float* wq = enc_wq + (long long)l * DD;
        const float* wk = enc_wk + (long long)l * DD;
        const float* wv = enc_wv + (long long)l * DD;
        const float* wo = enc_wo + (long long)l * DD;
        const float* bo = enc_bo + (long long)l * DMODEL;

        g_launch(stream, mb16, DMODEL, 0, wq, DMODEL, 0, 1, nullptr, qb, DMODEL, 0, 1,
                 SEQ, DMODEL, DMODEL, 1.0f, 0, 0, 1);
        g_launch(stream, mb16, DMODEL, 0, wk, DMODEL, 0, 1, nullptr, kb, DMODEL, 0, 1,
                 SEQ, DMODEL, DMODEL, 1.0f, 0, 0, 1);
        g_launch(stream, mb16, DMODEL, 0, wv, DMODEL, 0, 1, nullptr, vb, DMODEL, 0, 1,
                 SEQ, DMODEL, DMODEL, 1.0f, 0, 0, 1);
        hipLaunchKernelGGL(transpose_bf16, dim3(DMODEL / 64, SEQ / 64), dim3(256), 0, stream, vb, vt);
        g_launch(stream, qb, DMODEL, DHEAD, kb, DMODEL, DHEAD, 0, nullptr, pb, SEQ, SS, 1,
                 SEQ, SEQ, DHEAD, 0.125f, 0, 0, NHEAD);
        hipLaunchKernelGGL(softmax_bf16, dim3(NHEAD * SEQ), dim3(256), 0, stream, pb);
        g_launch(stream, pb, SEQ, SS, vt, SEQ, (long long)DHEAD * SEQ, 0, nullptr, ob, DMODEL, DHEAD, 1,
                 SEQ, DHEAD, SEQ, 1.0f, 0, 0, NHEAD);
        g_launch(stream, ob, DMODEL, 0, wo, DMODEL, 0, 1, bo, fbuf, DMODEL, 0, 0,
                 SEQ, DMODEL, DMODEL, 1.0f, 0, 0, 1);
        hipLaunchKernelGGL(ln_res_kernel, dim3(SEQ), dim3(256), 0, stream,
                           mbuf, fbuf, enc_lna + (long long)(l * 2 + 0) * DMODEL,
                           enc_lnb + (long long)(l * 2 + 0) * DMODEL, mb16);
        g_launch(stream, mb16, DMODEL, 0, enc_w1 + (long long)l * WH, DMODEL, 0, 1,
                 enc_b1 + (long long)l * HIDDEN, hb, HIDDEN, 0, 1,
                 SEQ, HIDDEN, DMODEL, 1.0f, 1, 0, 1);
        g_launch(stream, hb, HIDDEN, 0, enc_w2 + (long long)l * WH, HIDDEN, 0, 1,
                 enc_b2 + (long long)l * DMODEL, fbuf, DMODEL, 0, 0,
                 SEQ, DMODEL, HIDDEN, 1.0f, 0, 0, 1);
        hipLaunchKernelGGL(ln_res_kernel, dim3(SEQ), dim3(256), 0, stream,
                           mbuf, fbuf, enc_lna + (long long)(l * 2 + 1) * DMODEL,
                           enc_lnb + (long long)(l * 2 + 1) * DMODEL, mb16);
    }

    hipLaunchKernelGGL(add_pe, dim3((int)(AC / 256)), dim3(256), 0, stream, dl, pe, xbuf, xb16, (int)AC);

    // ---------------- decoder ----------------
    for (int l = 0; l < NLAYER; ++l) {
        // self attention (causal)
        g_launch(stream, xb16, DMODEL, 0, dec_wq + (long long)l * DD, DMODEL, 0, 1, nullptr, qb, DMODEL, 0, 1,
                 SEQ, DMODEL, DMODEL, 1.0f, 0, 0, 1);
        g_launch(stream, xb16, DMODEL, 0, dec_wk + (long long)l * DD, DMODEL, 0, 1, nullptr, kb, DMODEL, 0, 1,
                 SEQ, DMODEL, DMODEL, 1.0f, 0, 0, 1);
        g_launch(stream, xb16, DMODEL, 0, dec_wv + (long long)l * DD, DMODEL, 0, 1, nullptr, vb, DMODEL, 0, 1,
                 SEQ, DMODEL, DMODEL, 1.0f, 0, 0, 1);
        hipLaunchKernelGGL(transpose_bf16, dim3(DMODEL / 64, SEQ / 64), dim3(256), 0, stream, vb, vt);
        g_launch(stream, qb, DMODEL, DHEAD, kb, DMODEL, DHEAD, 0, nullptr, pb, SEQ, SS, 1,
                 SEQ, SEQ, DHEAD, 0.125f, 0, 1, NHEAD);
        hipLaunchKernelGGL(softmax_bf16, dim3(NHEAD * SEQ), dim3(256), 0, stream, pb);
        g_launch(stream, pb, SEQ, SS, vt, SEQ, (long long)DHEAD * SEQ, 0, nullptr, ob, DMODEL, DHEAD, 1,
                 SEQ, DHEAD, SEQ, 1.0f, 0, 0, NHEAD);
        g_launch(stream, ob, DMODEL, 0, dec_wo + (long long)l * DD, DMODEL, 0, 1,
                 dec_bo + (long long)l * DMODEL, fbuf, DMODEL, 0, 0,
                 SEQ, DMODEL, DMODEL, 1.0f, 0, 0, 1);
        hipLaunchKernelGGL(ln_res_kernel, dim3(SEQ), dim3(256), 0, stream,
                           xbuf, fbuf, dec_lna + (long long)(l * 3 + 0) * DMODEL,
                           dec_lnb + (long long)(l * 3 + 0) * DMODEL, xb16);

        // cross attention
        g_launch(stream, xb16, DMODEL, 0, dec_cwq + (long long)l * DD, DMODEL, 0, 1, nullptr, qb, DMODEL, 0, 1,
                 SEQ, DMODEL, DMODEL, 1.0f, 0, 0, 1);
        g_launch(stream, mb16, DMODEL, 0, dec_cwk + (long long)l * DD, DMODEL, 0, 1, nullptr, kb, DMODEL, 0, 1,
                 SEQ, DMODEL, DMODEL, 1.0f, 0, 0, 1);
        g_launch(stream, mb16, DMODEL, 0, dec_cwv + (long long)l * DD, DMODEL, 0, 1, nullptr, vb, DMODEL, 0, 1,
                 SEQ, DMODEL, DMODEL, 1.0f, 0, 0, 1);
        hipLaunchKernelGGL(transpose_bf16, dim3(DMODEL / 64, SEQ / 64), dim3(256), 0, stream, vb, vt);
        g_launch(stream, qb, DMODEL, DHEAD, kb, DMODEL, DHEAD, 0, nullptr, pb, SEQ, SS, 1,
                 SEQ, SEQ, DHEAD, 0.125f, 0, 0, NHEAD);
        hipLaunchKernelGGL(softmax_bf16, dim3(NHEAD * SEQ), dim3(256), 0, stream, pb);
        g_launch(stream, pb, SEQ, SS, vt, SEQ, (long long)DHEAD * SEQ, 0, nullptr, ob, DMODEL, DHEAD, 1,
                 SEQ, DHEAD, SEQ, 1.0f, 0, 0, NHEAD);
        g_launch(stream, ob, DMODEL, 0, dec_cwo + (long long)l * DD, DMODEL, 0, 1,
                 dec_cbo + (long long)l * DMODEL, fbuf, DMODEL, 0, 0,
                 SEQ, DMODEL, DMODEL, 1.0f, 0, 0, 1);
        hipLaunchKernelGGL(ln_res_kernel, dim3(SEQ), dim3(256), 0, stream,
                           xbuf, fbuf, dec_lna + (long long)(l * 3 + 1) * DMODEL,
                           dec_lnb + (long long)(l * 3 + 1) * DMODEL, xb16);

        // FFN
        g_launch(stream, xb16, DMODEL, 0, dec_w1 + (long long)l * WH, DMODEL, 0, 1,
                 dec_b1 + (long long)l * HIDDEN, hb, HIDDEN, 0, 1,
                 SEQ, HIDDEN, DMODEL, 1.0f, 1, 0, 1);
        g_launch(stream, hb, HIDDEN, 0, dec_w2 + (long long)l * WH, HIDDEN, 0, 1,
                 dec_b2 + (long long)l * DMODEL, fbuf, DMODEL, 0, 0,
                 SEQ, DMODEL, HIDDEN, 1.0f, 0, 0, 1);
        hipLaunchKernelGGL(ln_res_kernel, dim3(SEQ), dim3(256), 0, stream,
                           xbuf, fbuf, dec_lna + (long long)(l * 3 + 2) * DMODEL,
                           dec_lnb + (long long)(l * 3 + 2) * DMODEL, xb16);
    }

    hipLaunchKernelGGL(softmax_f32, dim3(SEQ), dim3(256), 0, stream, xbuf, (float*)d_out, DMODEL);
}

// Round 3
// 2676.575 us; speedup vs baseline: 2.7834x; 1.2258x over previous
//
#include <hip/hip_runtime.h>
#include <math.h>

#define DMODEL 768
#define NHEAD 12
#define DHEAD 64
#define HIDDEN 3072
#define NLAYER 6
#define SEQ 1024

typedef unsigned short u16;
typedef __attribute__((ext_vector_type(8))) short short8;
typedef __attribute__((ext_vector_type(4))) float f32x4;

__device__ __forceinline__ u16 f2bf(float f) {
    union { float f; unsigned u; } v; v.f = f;
    unsigned u = v.u;
    return (u16)((u + 0x7fffu + ((u >> 16) & 1u)) >> 16);
}
__device__ __forceinline__ float bf2f(u16 b) {
    union { unsigned u; float f; } v; v.u = ((unsigned)b) << 16; return v.f;
}

// async global->LDS, 16B per lane; LDS base must be wave-uniform (HW adds lane*16)
__device__ __forceinline__ void async16(const void* g, void* l) {
    __builtin_amdgcn_global_load_lds(
        (const __attribute__((address_space(1))) unsigned int*)g,
        (__attribute__((address_space(3))) unsigned int*)l, 16, 0, 0);
}

// ---------------------------------------------------------------- reductions
__device__ __forceinline__ float block_sum(float v, float* red) {
    int tid = threadIdx.x;
    red[tid] = v;
    __syncthreads();
#pragma unroll
    for (int s = 128; s > 0; s >>= 1) {
        if (tid < s) red[tid] += red[tid + s];
        __syncthreads();
    }
    float r = red[0];
    __syncthreads();
    return r;
}
__device__ __forceinline__ float block_max(float v, float* red) {
    int tid = threadIdx.x;
    red[tid] = v;
    __syncthreads();
#pragma unroll
    for (int s = 128; s > 0; s >>= 1) {
        if (tid < s) red[tid] = fmaxf(red[tid], red[tid + s]);
        __syncthreads();
    }
    float r = red[0];
    __syncthreads();
    return r;
}

// ---------------------------------------------------------------- small kernels
__global__ __launch_bounds__(256) void add_pe(const float* __restrict__ a,
                                              const float* __restrict__ b,
                                              float* __restrict__ o,
                                              u16* __restrict__ ob, int n) {
    int i = blockIdx.x * 256 + threadIdx.x;
    if (i < n) { float v = a[i] + b[i]; o[i] = v; ob[i] = f2bf(v); }
}

__global__ __launch_bounds__(256) void cvt_bf16(const float* __restrict__ src,
                                                u16* __restrict__ dst,
                                                long long per, long long sls, long long dls) {
    long long i = ((long long)blockIdx.x * 256 + threadIdx.x) * 4;
    if (i >= per) return;
    const float* s = src + (long long)blockIdx.y * sls + i;
    u16* d = dst + (long long)blockIdx.y * dls + i;
    float4 v = *(const float4*)s;
    ushort4 o;
    o.x = f2bf(v.x); o.y = f2bf(v.y); o.z = f2bf(v.z); o.w = f2bf(v.w);
    *(ushort4*)d = o;
}

// ---------------------------------------------------------------- MFMA GEMM
// C[N x M] = alpha * A[N x K] * B[M x K]^T (+bias) (+relu) (+causal)
// A bf16 k-contiguous; B bf16 (async path) or fp32 (reg-staged convert).
// LDS: linear [rows][64] per tile, chunk index (8 chunks of 16B per row)
// XOR-swizzled by (row&7): source pre-swizzle on stage, XOR on ds_read.
template<int TM, int TN>
__global__ __launch_bounds__(256) void gemm_mfma(
    const u16* __restrict__ A, int lda, long long Aoff,
    const void* __restrict__ Bp, int ldb, long long Boff, int b_f32,
    const float* __restrict__ bias,
    void* __restrict__ Cp, int ldc, long long Coff, int c_bf16,
    int K, float alpha, int causal, int relu, int pvcausal)
{
    constexpr int FM = TM / 32, FN = TN / 32;  // frags per wave (waves 2x2)
    __shared__ __align__(16) u16 As[TM * 64];
    __shared__ __align__(16) u16 Bs[TN * 64];

    A += (long long)blockIdx.z * Aoff;
    const u16*   B16 = (const u16*)Bp   + (long long)blockIdx.z * Boff;
    const float* B32 = (const float*)Bp + (long long)blockIdx.z * Boff;
    u16*   C16 = (u16*)Cp   + (long long)blockIdx.z * Coff;
    float* C32 = (float*)Cp + (long long)blockIdx.z * Coff;

    const int t = threadIdx.x, lane = t & 63, w = t >> 6;
    const int wy = w >> 1, wx = w & 1;
    const int n0 = blockIdx.y * TM, m0 = blockIdx.x * TN;

    // fully-masked causal block: exact result is exp(-1e4...)->0; write mask value only
    if (causal && m0 >= n0 + TM) {
        const u16 neg = f2bf(-10000.0f);
        for (int e = t; e < TM * TN; e += 256) {
            int r = e / TN, c = e % TN;
            if (c_bf16) C16[(long long)(n0 + r) * ldc + m0 + c] = neg;
            else        C32[(long long)(n0 + r) * ldc + m0 + c] = -10000.0f;
        }
        return;
    }

    // causal PV: P[row][k]==0 exactly for k>row -> cap K at block diagonal
    const int Kend = pvcausal ? min(K, n0 + TM) : K;

    f32x4 acc[FM][FN] = {};

    for (int k0 = 0; k0 < Kend; k0 += 64) {
        // stage A (always bf16, async)
#pragma unroll
        for (int i = 0; i < TM / 32; ++i) {
            int L = i * 256 + t;
            int row = L >> 3, cp = L & 7, c = cp ^ (row & 7);
            async16(A + (long long)(n0 + row) * lda + k0 + (c << 3),
                    &As[(i * 256 + w * 64) * 8]);
        }
        if (!b_f32) {
#pragma unroll
            for (int i = 0; i < TN / 32; ++i) {
                int L = i * 256 + t;
                int row = L >> 3, cp = L & 7, c = cp ^ (row & 7);
                async16(B16 + (long long)(m0 + row) * ldb + k0 + (c << 3),
                        &Bs[(i * 256 + w * 64) * 8]);
            }
        } else {
#pragma unroll
            for (int i = 0; i < TN / 32; ++i) {
                int L = i * 256 + t;
                int row = L >> 3, cp = L & 7, c = cp ^ (row & 7);
                const float* s = B32 + (long long)(m0 + row) * ldb + k0 + (c << 3);
                float4 x = *(const float4*)s;
                float4 y = *(const float4*)(s + 4);
                uint4 pk;
                pk.x = (unsigned)f2bf(x.x) | ((unsigned)f2bf(x.y) << 16);
                pk.y = (unsigned)f2bf(x.z) | ((unsigned)f2bf(x.w) << 16);
                pk.z = (unsigned)f2bf(y.x) | ((unsigned)f2bf(y.y) << 16);
                pk.w = (unsigned)f2bf(y.z) | ((unsigned)f2bf(y.w) << 16);
                *(uint4*)&Bs[row * 64 + cp * 8] = pk;
            }
        }
        __syncthreads();  // drains vmcnt (async LDS) + lgkmcnt

#pragma unroll
        for (int kk = 0; kk < 2; ++kk) {
            short8 af[FM], bfv[FN];
            const int cbase = kk * 4 + (lane >> 4);
#pragma unroll
            for (int m = 0; m < FM; ++m) {
                int R = wy * (TM / 2) + m * 16 + (lane & 15);
                af[m] = *(const short8*)&As[R * 64 + ((cbase ^ (R & 7)) << 3)];
            }
#pragma unroll
            for (int n = 0; n < FN; ++n) {
                int R = wx * (TN / 2) + n * 16 + (lane & 15);
                bfv[n] = *(const short8*)&Bs[R * 64 + ((cbase ^ (R & 7)) << 3)];
            }
#pragma unroll
            for (int m = 0; m < FM; ++m)
#pragma unroll
                for (int n = 0; n < FN; ++n)
                    acc[m][n] = __builtin_amdgcn_mfma_f32_16x16x32_bf16(af[m], bfv[n], acc[m][n], 0, 0, 0);
        }
        __syncthreads();
    }

    // epilogue: C/D layout col=lane&15 (B rows), row=(lane>>4)*4+reg (A rows)
    const int cj = lane & 15, ci0 = (lane >> 4) << 2;
#pragma unroll
    for (int m = 0; m < FM; ++m) {
#pragma unroll
        for (int n = 0; n < FN; ++n) {
            int col = m0 + wx * (TN / 2) + n * 16 + cj;
            float bv = bias ? bias[col] : 0.0f;
#pragma unroll
            for (int r = 0; r < 4; ++r) {
                int row = n0 + wy * (TM / 2) + m * 16 + ci0 + r;
                float v = acc[m][n][r] * alpha + bv;
                if (relu) v = fmaxf(v, 0.0f);
                if (causal && col > row) v -= 10000.0f;
                if (c_bf16) C16[(long long)row * ldc + col] = f2bf(v);
                else        C32[(long long)row * ldc + col] = v;
            }
        }
    }
}

// ---------------------------------------------------------------- bf16 transpose: in [1024 x ld_in] slice -> out [768 x 1024]
__global__ __launch_bounds__(256) void transpose_bf16(const u16* __restrict__ in, int ld_in,
                                                      u16* __restrict__ out) {
    __shared__ u16 T[64][72];
    int bi = blockIdx.x;   // input col block (0..11)
    int bj = blockIdx.y;   // input row block (0..15)
    int tid = threadIdx.x;
    int r = tid >> 3, c8 = (tid & 7) << 3;
#pragma unroll
    for (int i = 0; i < 2; ++i) {
        int row = r + i * 32;
        uint4 v = *(const uint4*)(in + (long long)(bj * 64 + row) * ld_in + bi * 64 + c8);
        *(uint4*)&T[row][c8] = v;
    }
    __syncthreads();
#pragma unroll
    for (int i = 0; i < 2; ++i) {
        int row = r + i * 32;
        unsigned p0 = (unsigned)T[c8 + 0][row] | ((unsigned)T[c8 + 1][row] << 16);
        unsigned p1 = (unsigned)T[c8 + 2][row] | ((unsigned)T[c8 + 3][row] << 16);
        unsigned p2 = (unsigned)T[c8 + 4][row] | ((unsigned)T[c8 + 5][row] << 16);
        unsigned p3 = (unsigned)T[c8 + 6][row] | ((unsigned)T[c8 + 7][row] << 16);
        uint4 wv = {p0, p1, p2, p3};
        *(uint4*)(out + (long long)(bi * 64 + row) * SEQ + bj * 64 + c8) = wv;
    }
}

// ---------------------------------------------------------------- softmax over bf16 rows of 1024, in place
__global__ __launch_bounds__(256) void softmax_bf16(u16* __restrict__ p) {
    u16* row = p + (long long)blockIdx.x * SEQ;
    int tid = threadIdx.x;
    __shared__ float red[256];
    ushort4 r4 = ((const ushort4*)row)[tid];
    float x0 = bf2f(r4.x), x1 = bf2f(r4.y), x2 = bf2f(r4.z), x3 = bf2f(r4.w);
    float mx = fmaxf(fmaxf(x0, x1), fmaxf(x2, x3));
    mx = block_max(mx, red);
    float e0 = __expf(x0 - mx), e1 = __expf(x1 - mx), e2 = __expf(x2 - mx), e3 = __expf(x3 - mx);
    float s = e0 + e1 + e2 + e3;
    s = block_sum(s, red);
    float inv = 1.0f / s;
    ushort4 o;
    o.x = f2bf(e0 * inv); o.y = f2bf(e1 * inv); o.z = f2bf(e2 * inv); o.w = f2bf(e3 * inv);
    ((ushort4*)row)[tid] = o;
}

// ---------------------------------------------------------------- f32 row softmax
__global__ __launch_bounds__(256) void softmax_f32(const float* __restrict__ in,
                                                   float* __restrict__ out, int width) {
    const float* row = in + (long long)blockIdx.x * width;
    float* orow = out + (long long)blockIdx.x * width;
    int tid = threadIdx.x;
    __shared__ float red[256];
    int nf4 = width >> 2;
    float4 v = {-1e30f, -1e30f, -1e30f, -1e30f};
    if (tid < nf4) v = ((const float4*)row)[tid];
    float mx = fmaxf(fmaxf(v.x, v.y), fmaxf(v.z, v.w));
    mx = block_max(mx, red);
    float4 e = {0.f, 0.f, 0.f, 0.f};
    float s = 0.f;
    if (tid < nf4) {
        e.x = __expf(v.x - mx); e.y = __expf(v.y - mx);
        e.z = __expf(v.z - mx); e.w = __expf(v.w - mx);
        s = e.x + e.y + e.z + e.w;
    }
    s = block_sum(s, red);
    float inv = 1.0f / s;
    if (tid < nf4) {
        e.x *= inv; e.y *= inv; e.z *= inv; e.w *= inv;
        ((float4*)orow)[tid] = e;
    }
}

// ---------------------------------------------------------------- x = LN(x + fx); emits f32 + bf16
__global__ __launch_bounds__(256) void ln_res_kernel(float* __restrict__ x,
                                                     const float* __restrict__ fx,
                                                     const float* __restrict__ ga,
                                                     const float* __restrict__ gb,
                                                     u16* __restrict__ xb) {
    long long row = blockIdx.x;
    float* xr = x + row * DMODEL;
    const float* fr = fx + row * DMODEL;
    u16* xbr = xb + row * DMODEL;
    int tid = threadIdx.x;
    __shared__ float red[256];

    float4 tv = {0.f, 0.f, 0.f, 0.f};
    if (tid < 192) {
        float4 a = ((const float4*)xr)[tid];
        float4 f = ((const float4*)fr)[tid];
        tv.x = a.x + f.x; tv.y = a.y + f.y; tv.z = a.z + f.z; tv.w = a.w + f.w;
    }
    float sum = tv.x + tv.y + tv.z + tv.w;
    sum = block_sum(sum, red);
    float mean = sum * (1.0f / (float)DMODEL);

    float4 d = {0.f, 0.f, 0.f, 0.f};
    float ss = 0.f;
    if (tid < 192) {
        d.x = tv.x - mean; d.y = tv.y - mean; d.z = tv.z - mean; d.w = tv.w - mean;
        ss = d.x * d.x + d.y * d.y + d.z * d.z + d.w * d.w;
    }
    ss = block_sum(ss, red);
    float stdv = sqrtf(ss / (float)(DMODEL - 1));
    float inv = 1.0f / (stdv + 1e-6f);

    if (tid < 192) {
        float4 A = ((const float4*)ga)[tid];
        float4 B = ((const float4*)gb)[tid];
        float4 o;
        o.x = A.x * d.x * inv + B.x;
        o.y = A.y * d.y * inv + B.y;
        o.z = A.z * d.z * inv + B.z;
        o.w = A.w * d.w * inv + B.w;
        ((float4*)xr)[tid] = o;
        ushort4 ob;
        ob.x = f2bf(o.x); ob.y = f2bf(o.y); ob.z = f2bf(o.z); ob.w = f2bf(o.w);
        ((ushort4*)xbr)[tid] = ob;
    }
}

// ---------------------------------------------------------------- host
struct GArg {
    const u16* A; int lda; long long Aoff;
    const void* B; int ldb; long long Boff; int b_f32;
    const float* bias;
    void* C; int ldc; long long Coff; int c_bf16;
    int N, M, K; float alpha; int causal, relu, pvcausal, batch;
};

static inline void g128(hipStream_t st, const GArg& a) {
    dim3 grid(a.M / 128, a.N / 128, a.batch);
    hipLaunchKernelGGL((gemm_mfma<128, 128>), grid, dim3(256), 0, st,
                       a.A, a.lda, a.Aoff, a.B, a.ldb, a.Boff, a.b_f32, a.bias,
                       a.C, a.ldc, a.Coff, a.c_bf16, a.K, a.alpha, a.causal, a.relu, a.pvcausal);
}
static inline void g64(hipStream_t st, const GArg& a) {
    dim3 grid(a.M / 64, a.N / 64, a.batch);
    hipLaunchKernelGGL((gemm_mfma<64, 64>), grid, dim3(256), 0, st,
                       a.A, a.lda, a.Aoff, a.B, a.ldb, a.Boff, a.b_f32, a.bias,
                       a.C, a.ldc, a.Coff, a.c_bf16, a.K, a.alpha, a.causal, a.relu, a.pvcausal);
}

extern "C" void kernel_launch(void* const* d_in, const int* in_sizes, int n_in,
                              void* d_out, int out_size, void* d_ws, size_t ws_size,
                              hipStream_t stream) {
    const float* xl      = (const float*)d_in[0];
    const float* dl      = (const float*)d_in[1];
    const float* pe      = (const float*)d_in[2];
    const float* enc_wq  = (const float*)d_in[3];
    const float* enc_wk  = (const float*)d_in[4];
    const float* enc_wv  = (const float*)d_in[5];
    const float* enc_wo  = (const float*)d_in[6];
    const float* enc_bo  = (const float*)d_in[7];
    const float* enc_lna = (const float*)d_in[8];
    const float* enc_lnb = (const float*)d_in[9];
    const float* enc_w1  = (const float*)d_in[10];
    const float* enc_b1  = (const float*)d_in[11];
    const float* enc_w2  = (const float*)d_in[12];
    const float* enc_b2  = (const float*)d_in[13];
    const float* dec_wq  = (const float*)d_in[14];
    const float* dec_wk  = (const float*)d_in[15];
    const float* dec_wv  = (const float*)d_in[16];
    const float* dec_wo  = (const float*)d_in[17];
    const float* dec_bo  = (const float*)d_in[18];
    const float* dec_cwq = (const float*)d_in[19];
    const float* dec_cwk = (const float*)d_in[20];
    const float* dec_cwv = (const float*)d_in[21];
    const float* dec_cwo = (const float*)d_in[22];
    const float* dec_cbo = (const float*)d_in[23];
    const float* dec_lna = (const float*)d_in[24];
    const float* dec_lnb = (const float*)d_in[25];
    const float* dec_w1  = (const float*)d_in[26];
    const float* dec_b1  = (const float*)d_in[27];
    const float* dec_w2  = (const float*)d_in[28];
    const float* dec_b2  = (const float*)d_in[29];

    const long long AC   = (long long)SEQ * DMODEL;     // 786432
    const long long SS   = (long long)SEQ * SEQ;        // 1048576
    const long long DD   = (long long)DMODEL * DMODEL;  // 589824
    const long long WH   = (long long)HIDDEN * DMODEL;  // 2359296
    const long long QKVC = (long long)SEQ * 3 * DMODEL; // 2359296
    const long long SH   = (long long)SEQ * HIDDEN;     // 3145728

    float* mbuf = (float*)d_ws;
    float* xbuf = mbuf + AC;
    float* fbuf = xbuf + AC;
    u16* u = (u16*)(fbuf + AC);
    u16* mb16 = u;  u += AC;
    u16* xb16 = u;  u += AC;
    u16* qkvb = u;  u += QKVC;      // [1024][2304]: q | k | v
    u16* vt   = u;  u += AC;        // V^T [768][1024]
    u16* ob   = u;  u += AC;        // attention out
    u16* hb   = u;  u += SH;        // ffn hidden
    u16* pb   = u;  u += (long long)NHEAD * SS;  // probs

    // converted-weight region (if it fits)
    u16* W = u;
    long long woff = 0;
    const long long W_ENC_QKV = woff; woff += 18 * DD;
    const long long W_ENC_WO  = woff; woff += 6 * DD;
    const long long W_ENC_W1  = woff; woff += 6 * WH;
    const long long W_ENC_W2  = woff; woff += 6 * WH;
    const long long W_DEC_QKV = woff; woff += 18 * DD;
    const long long W_DEC_CQKV= woff; woff += 18 * DD;
    const long long W_DEC_WO  = woff; woff += 6 * DD;
    const long long W_DEC_CWO = woff; woff += 6 * DD;
    const long long W_DEC_W1  = woff; woff += 6 * WH;
    const long long W_DEC_W2  = woff; woff += 6 * WH;
    const long long need = (long long)((char*)(W + woff) - (char*)d_ws);
    const bool conv = ((long long)ws_size >= need);

    if (conv) {
        auto cvt = [&](const float* src, long long dst_off, long long per, long long sls, long long dls, int L) {
            dim3 grid((unsigned)((per / 4 + 255) / 256), L);
            hipLaunchKernelGGL(cvt_bf16, grid, dim3(256), 0, stream, src, W + dst_off, per, sls, dls);
        };
        cvt(enc_wq, W_ENC_QKV + 0 * DD, DD, DD, 3 * DD, NLAYER);
        cvt(enc_wk, W_ENC_QKV + 1 * DD, DD, DD, 3 * DD, NLAYER);
        cvt(enc_wv, W_ENC_QKV + 2 * DD, DD, DD, 3 * DD, NLAYER);
        cvt(enc_wo, W_ENC_WO, 6 * DD, 0, 0, 1);
        cvt(enc_w1, W_ENC_W1, 6 * WH, 0, 0, 1);
        cvt(enc_w2, W_ENC_W2, 6 * WH, 0, 0, 1);
        cvt(dec_wq, W_DEC_QKV + 0 * DD, DD, DD, 3 * DD, NLAYER);
        cvt(dec_wk, W_DEC_QKV + 1 * DD, DD, DD, 3 * DD, NLAYER);
        cvt(dec_wv, W_DEC_QKV + 2 * DD, DD, DD, 3 * DD, NLAYER);
        cvt(dec_cwq, W_DEC_CQKV + 0 * DD, DD, DD, 3 * DD, NLAYER);
        cvt(dec_cwk, W_DEC_CQKV + 1 * DD, DD, DD, 3 * DD, NLAYER);
        cvt(dec_cwv, W_DEC_CQKV + 2 * DD, DD, DD, 3 * DD, NLAYER);
        cvt(dec_wo, W_DEC_WO, 6 * DD, 0, 0, 1);
        cvt(dec_cwo, W_DEC_CWO, 6 * DD, 0, 0, 1);
        cvt(dec_w1, W_DEC_W1, 6 * WH, 0, 0, 1);
        cvt(dec_w2, W_DEC_W2, 6 * WH, 0, 0, 1);
    }

    hipLaunchKernelGGL(add_pe, dim3((int)(AC / 256)), dim3(256), 0, stream, xl, pe, mbuf, mb16, (int)AC);

    // attention core (shared by enc-self / dec-self / dec-cross)
    auto attention_core = [&](int causal) {
        hipLaunchKernelGGL(transpose_bf16, dim3(DMODEL / 64, SEQ / 64), dim3(256), 0, stream,
                           qkvb + 2 * DMODEL, 3 * DMODEL, vt);
        GArg sc = { qkvb, 3 * DMODEL, DHEAD, qkvb + DMODEL, 3 * DMODEL, DHEAD, 0, nullptr,
                    pb, SEQ, SS, 1, SEQ, SEQ, DHEAD, 0.125f, causal, 0, 0, NHEAD };
        g128(stream, sc);
        hipLaunchKernelGGL(softmax_bf16, dim3(NHEAD * SEQ), dim3(256), 0, stream, pb);
        GArg pv = { pb, SEQ, SS, vt, SEQ, (long long)DHEAD * SEQ, 0, nullptr,
                    ob, DMODEL, DHEAD, 1, SEQ, DHEAD, SEQ, 1.0f, 0, 0, causal, NHEAD };
        g64(stream, pv);
    };

    // ---------------- encoder ----------------
    for (int l = 0; l < NLAYER; ++l) {
        if (conv) {
            GArg qkv = { mb16, DMODEL, 0, W + W_ENC_QKV + l * 3 * DD, DMODEL, 0, 0, nullptr,
                         qkvb, 3 * DMODEL, 0, 1, SEQ, 3 * DMODEL, DMODEL, 1.0f, 0, 0, 0, 1 };
            g128(stream, qkv);
        } else {
            const float* wps[3] = { enc_wq + l * DD, enc_wk + l * DD, enc_wv + l * DD };
            for (int j = 0; j < 3; ++j) {
                GArg a = { mb16, DMODEL, 0, wps[j], DMODEL, 0, 1, nullptr,
                           qkvb + j * DMODEL, 3 * DMODEL, 0, 1, SEQ, DMODEL, DMODEL, 1.0f, 0, 0, 0, 1 };
                g64(stream, a);
            }
        }
        attention_core(0);
        GArg wo = { ob, DMODEL, 0,
                    conv ? (const void*)(W + W_ENC_WO + l * DD) : (const void*)(enc_wo + l * DD),
                    DMODEL, 0, conv ? 0 : 1, enc_bo + (long long)l * DMODEL,
                    fbuf, DMODEL, 0, 0, SEQ, DMODEL, DMODEL, 1.0f, 0, 0, 0, 1 };
        g64(stream, wo);
        hipLaunchKernelGGL(ln_res_kernel, dim3(SEQ), dim3(256), 0, stream,
                           mbuf, fbuf, enc_lna + (long long)(l * 2 + 0) * DMODEL,
                           enc_lnb + (long long)(l * 2 + 0) * DMODEL, mb16);
        GArg f1 = { mb16, DMODEL, 0,
                    conv ? (const void*)(W + W_ENC_W1 + l * WH) : (const void*)(enc_w1 + l * WH),
                    DMODEL, 0, conv ? 0 : 1, enc_b1 + (long long)l * HIDDEN,
                    hb, HIDDEN, 0, 1, SEQ, HIDDEN, DMODEL, 1.0f, 0, 1, 0, 1 };
        g128(stream, f1);
        GArg f2 = { hb, HIDDEN, 0,
                    conv ? (const void*)(W + W_ENC_W2 + l * WH) : (const void*)(enc_w2 + l * WH),
                    HIDDEN, 0, conv ? 0 : 1, enc_b2 + (long long)l * DMODEL,
                    fbuf, DMODEL, 0, 0, SEQ, DMODEL, HIDDEN, 1.0f, 0, 0, 0, 1 };
        g64(stream, f2);
        hipLaunchKernelGGL(ln_res_kernel, dim3(SEQ), dim3(256), 0, stream,
                           mbuf, fbuf, enc_lna + (long long)(l * 2 + 1) * DMODEL,
                           enc_lnb + (long long)(l * 2 + 1) * DMODEL, mb16);
    }

    hipLaunchKernelGGL(add_pe, dim3((int)(AC / 256)), dim3(256), 0, stream, dl, pe, xbuf, xb16, (int)AC);

    // ---------------- decoder ----------------
    for (int l = 0; l < NLAYER; ++l) {
        // self attention (causal)
        if (conv) {
            GArg qkv = { xb16, DMODEL, 0, W + W_DEC_QKV + l * 3 * DD, DMODEL, 0, 0, nullptr,
                         qkvb, 3 * DMODEL, 0, 1, SEQ, 3 * DMODEL, DMODEL, 1.0f, 0, 0, 0, 1 };
            g128(stream, qkv);
        } else {
            const float* wps[3] = { dec_wq + l * DD, dec_wk + l * DD, dec_wv + l * DD };
            for (int j = 0; j < 3; ++j) {
                GArg a = { xb16, DMODEL, 0, wps[j], DMODEL, 0, 1, nullptr,
                           qkvb + j * DMODEL, 3 * DMODEL, 0, 1, SEQ, DMODEL, DMODEL, 1.0f, 0, 0, 0, 1 };
                g64(stream, a);
            }
        }
        attention_core(1);
        GArg wo = { ob, DMODEL, 0,
                    conv ? (const void*)(W + W_DEC_WO + l * DD) : (const void*)(dec_wo + l * DD),
                    DMODEL, 0, conv ? 0 : 1, dec_bo + (long long)l * DMODEL,
                    fbuf, DMODEL, 0, 0, SEQ, DMODEL, DMODEL, 1.0f, 0, 0, 0, 1 };
        g64(stream, wo);
        hipLaunchKernelGGL(ln_res_kernel, dim3(SEQ), dim3(256), 0, stream,
                           xbuf, fbuf, dec_lna + (long long)(l * 3 + 0) * DMODEL,
                           dec_lnb + (long long)(l * 3 + 0) * DMODEL, xb16);

        // cross attention: Q from decoder, K/V from encoder memory
        if (conv) {
            GArg q = { xb16, DMODEL, 0, W + W_DEC_CQKV + l * 3 * DD, DMODEL, 0, 0, nullptr,
                       qkvb, 3 * DMODEL, 0, 1, SEQ, DMODEL, DMODEL, 1.0f, 0, 0, 0, 1 };
            g64(stream, q);
            GArg kv = { mb16, DMODEL, 0, W + W_DEC_CQKV + l * 3 * DD + DD, DMODEL, 0, 0, nullptr,
                        qkvb + DMODEL, 3 * DMODEL, 0, 1, SEQ, 2 * DMODEL, DMODEL, 1.0f, 0, 0, 0, 1 };
            g128(stream, kv);
        } else {
            GArg q = { xb16, DMODEL, 0, dec_cwq + l * DD, DMODEL, 0, 1, nullptr,
                       qkvb, 3 * DMODEL, 0, 1, SEQ, DMODEL, DMODEL, 1.0f, 0, 0, 0, 1 };
            g64(stream, q);
            const float* wps[2] = { dec_cwk + l * DD, dec_cwv + l * DD };
            for (int j = 0; j < 2; ++j) {
                GArg a = { mb16, DMODEL, 0, wps[j], DMODEL, 0, 1, nullptr,
                           qkvb + (j + 1) * DMODEL, 3 * DMODEL, 0, 1, SEQ, DMODEL, DMODEL, 1.0f, 0, 0, 0, 1 };
                g64(stream, a);
            }
        }
        attention_core(0);
        GArg cwo = { ob, DMODEL, 0,
                     conv ? (const void*)(W + W_DEC_CWO + l * DD) : (const void*)(dec_cwo + l * DD),
                     DMODEL, 0, conv ? 0 : 1, dec_cbo + (long long)l * DMODEL,
                     fbuf, DMODEL, 0, 0, SEQ, DMODEL, DMODEL, 1.0f, 0, 0, 0, 1 };
        g64(stream, cwo);
        hipLaunchKernelGGL(ln_res_kernel, dim3(SEQ), dim3(256), 0, stream,
                           xbuf, fbuf, dec_lna + (long long)(l * 3 + 1) * DMODEL,
                           dec_lnb + (long long)(l * 3 + 1) * DMODEL, xb16);

        // FFN
        GArg f1 = { xb16, DMODEL, 0,
                    conv ? (const void*)(W + W_DEC_W1 + l * WH) : (const void*)(dec_w1 + l * WH),
                    DMODEL, 0, conv ? 0 : 1, dec_b1 + (long long)l * HIDDEN,
                    hb, HIDDEN, 0, 1, SEQ, HIDDEN, DMODEL, 1.0f, 0, 1, 0, 1 };
        g128(stream, f1);
        GArg f2 = { hb, HIDDEN, 0,
                    conv ? (const void*)(W + W_DEC_W2 + l * WH) : (const void*)(dec_w2 + l * WH),
                    HIDDEN, 0, conv ? 0 : 1, dec_b2 + (long long)l * DMODEL,
                    fbuf, DMODEL, 0, 0, SEQ, DMODEL, HIDDEN, 1.0f, 0, 0, 0, 1 };
        g64(stream, f2);
        hipLaunchKernelGGL(ln_res_kernel, dim3(SEQ), dim3(256), 0, stream,
                           xbuf, fbuf, dec_lna + (long long)(l * 3 + 2) * DMODEL,
                           dec_lnb + (long long)(l * 3 + 2) * DMODEL, xb16);
    }

    hipLaunchKernelGGL(softmax_f32, dim3(SEQ), dim3(256), 0, stream, xbuf, (float*)d_out, DMODEL);
}

// Round 4
// 2171.570 us; speedup vs baseline: 3.4306x; 1.2326x over previous
//
#include <hip/hip_runtime.h>
#include <math.h>

#define DMODEL 768
#define NHEAD 12
#define DHEAD 64
#define HIDDEN 3072
#define NLAYER 6
#define SEQ 1024

typedef unsigned short u16;
typedef __attribute__((ext_vector_type(8))) short short8;
typedef __attribute__((ext_vector_type(4))) float f32x4;

__device__ __forceinline__ u16 f2bf(float f) {
    union { float f; unsigned u; } v; v.f = f;
    unsigned u = v.u;
    return (u16)((u + 0x7fffu + ((u >> 16) & 1u)) >> 16);
}
__device__ __forceinline__ float bf2f(u16 b) {
    union { unsigned u; float f; } v; v.u = ((unsigned)b) << 16; return v.f;
}

// async global->LDS, 16B/lane; LDS base wave-uniform (HW adds lane*16)
__device__ __forceinline__ void async16(const void* g, void* l) {
    __builtin_amdgcn_global_load_lds(
        (const __attribute__((address_space(1))) unsigned int*)g,
        (__attribute__((address_space(3))) unsigned int*)l, 16, 0, 0);
}

// ---------------------------------------------------------------- reductions
__device__ __forceinline__ float block_sum(float v, float* red) {
    int tid = threadIdx.x;
    red[tid] = v;
    __syncthreads();
#pragma unroll
    for (int s = 128; s > 0; s >>= 1) {
        if (tid < s) red[tid] += red[tid + s];
        __syncthreads();
    }
    float r = red[0];
    __syncthreads();
    return r;
}
__device__ __forceinline__ float block_max(float v, float* red) {
    int tid = threadIdx.x;
    red[tid] = v;
    __syncthreads();
#pragma unroll
    for (int s = 128; s > 0; s >>= 1) {
        if (tid < s) red[tid] = fmaxf(red[tid], red[tid + s]);
        __syncthreads();
    }
    float r = red[0];
    __syncthreads();
    return r;
}

// ---------------------------------------------------------------- small kernels
__global__ __launch_bounds__(256) void add_pe(const float* __restrict__ a,
                                              const float* __restrict__ b,
                                              float* __restrict__ o,
                                              u16* __restrict__ ob, int n) {
    int i = blockIdx.x * 256 + threadIdx.x;
    if (i < n) { float v = a[i] + b[i]; o[i] = v; ob[i] = f2bf(v); }
}

__global__ __launch_bounds__(256) void cvt_bf16(const float* __restrict__ src,
                                                u16* __restrict__ dst,
                                                long long per, long long sls, long long dls) {
    long long i = ((long long)blockIdx.x * 256 + threadIdx.x) * 4;
    if (i >= per) return;
    const float* s = src + (long long)blockIdx.y * sls + i;
    u16* d = dst + (long long)blockIdx.y * dls + i;
    float4 v = *(const float4*)s;
    ushort4 o;
    o.x = f2bf(v.x); o.y = f2bf(v.y); o.z = f2bf(v.z); o.w = f2bf(v.w);
    *(ushort4*)d = o;
}

// ---------------------------------------------------------------- MFMA GEMM
// C[N x M] = A[N x K](bf16) * B[M x K]^T (+bias) (+relu)
// Optional: columns >= vt_col0 are stored TRANSPOSED to vt_out[(col-vt_col0)][row]
// (used to produce V^T directly from the QKV projection).
template<int TM, int TN>
__global__ __launch_bounds__(256) void gemm_mfma(
    const u16* __restrict__ A, int lda,
    const void* __restrict__ Bp, int ldb, int b_f32,
    const float* __restrict__ bias,
    void* __restrict__ Cp, int ldc, int c_bf16,
    u16* __restrict__ vt_out, int vt_col0,
    int K, int relu)
{
    constexpr int FM = TM / 32, FN = TN / 32;
    __shared__ __align__(16) u16 As[TM * 64];
    __shared__ __align__(16) u16 Bs[TN * 64];

    const u16*   B16 = (const u16*)Bp;
    const float* B32 = (const float*)Bp;
    u16*   C16 = (u16*)Cp;
    float* C32 = (float*)Cp;

    const int t = threadIdx.x, lane = t & 63, w = t >> 6;
    const int wy = w >> 1, wx = w & 1;
    const int n0 = blockIdx.y * TM, m0 = blockIdx.x * TN;

    f32x4 acc[FM][FN] = {};

    for (int k0 = 0; k0 < K; k0 += 64) {
#pragma unroll
        for (int i = 0; i < TM / 32; ++i) {
            int L = i * 256 + t;
            int row = L >> 3, cp = L & 7, c = cp ^ (row & 7);
            async16(A + (long long)(n0 + row) * lda + k0 + (c << 3),
                    &As[(i * 256 + w * 64) * 8]);
        }
        if (!b_f32) {
#pragma unroll
            for (int i = 0; i < TN / 32; ++i) {
                int L = i * 256 + t;
                int row = L >> 3, cp = L & 7, c = cp ^ (row & 7);
                async16(B16 + (long long)(m0 + row) * ldb + k0 + (c << 3),
                        &Bs[(i * 256 + w * 64) * 8]);
            }
        } else {
#pragma unroll
            for (int i = 0; i < TN / 32; ++i) {
                int L = i * 256 + t;
                int row = L >> 3, cp = L & 7, c = cp ^ (row & 7);
                const float* s = B32 + (long long)(m0 + row) * ldb + k0 + (c << 3);
                float4 x = *(const float4*)s;
                float4 y = *(const float4*)(s + 4);
                uint4 pk;
                pk.x = (unsigned)f2bf(x.x) | ((unsigned)f2bf(x.y) << 16);
                pk.y = (unsigned)f2bf(x.z) | ((unsigned)f2bf(x.w) << 16);
                pk.z = (unsigned)f2bf(y.x) | ((unsigned)f2bf(y.y) << 16);
                pk.w = (unsigned)f2bf(y.z) | ((unsigned)f2bf(y.w) << 16);
                *(uint4*)&Bs[row * 64 + cp * 8] = pk;
            }
        }
        __syncthreads();

#pragma unroll
        for (int kk = 0; kk < 2; ++kk) {
            short8 af[FM], bfv[FN];
            const int cb = kk * 4 + (lane >> 4);
#pragma unroll
            for (int m = 0; m < FM; ++m) {
                int R = wy * (TM / 2) + m * 16 + (lane & 15);
                af[m] = *(const short8*)&As[R * 64 + (((cb ^ (R & 7))) << 3)];
            }
#pragma unroll
            for (int n = 0; n < FN; ++n) {
                int R = wx * (TN / 2) + n * 16 + (lane & 15);
                bfv[n] = *(const short8*)&Bs[R * 64 + (((cb ^ (R & 7))) << 3)];
            }
#pragma unroll
            for (int m = 0; m < FM; ++m)
#pragma unroll
                for (int n = 0; n < FN; ++n)
                    acc[m][n] = __builtin_amdgcn_mfma_f32_16x16x32_bf16(af[m], bfv[n], acc[m][n], 0, 0, 0);
        }
        __syncthreads();
    }

    const int cj = lane & 15, ci0 = (lane >> 4) << 2;
#pragma unroll
    for (int m = 0; m < FM; ++m) {
#pragma unroll
        for (int n = 0; n < FN; ++n) {
            int col = m0 + wx * (TN / 2) + n * 16 + cj;
            bool to_vt = vt_out && (col >= vt_col0);
            float bv = bias ? bias[col] : 0.0f;
#pragma unroll
            for (int r = 0; r < 4; ++r) {
                int row = n0 + wy * (TM / 2) + m * 16 + ci0 + r;
                float v = acc[m][n][r] + bv;
                if (relu) v = fmaxf(v, 0.0f);
                if (to_vt)        vt_out[(long long)(col - vt_col0) * SEQ + row] = f2bf(v);
                else if (c_bf16)  C16[(long long)row * ldc + col] = f2bf(v);
                else              C32[(long long)row * ldc + col] = v;
            }
        }
    }
}

// ---------------------------------------------------------------- fused flash attention
// grid (SEQ/64, NHEAD), 256 threads. Q,K from qkv buffer [SEQ][3*DMODEL];
// V^T [DMODEL][SEQ]; out O [SEQ][DMODEL]. softmax(QK^T/8 (+causal)) V.
template<int CAUSAL>
__global__ __launch_bounds__(256) void attn_fused(
    const u16* __restrict__ Qg,   // base of qkv buffer (Q columns)
    const u16* __restrict__ Kg,   // base + DMODEL (K columns)
    const u16* __restrict__ VT,   // [DMODEL][SEQ]
    u16* __restrict__ O)          // [SEQ][DMODEL]
{
    const int h  = blockIdx.y;
    const int qt = blockIdx.x;
    const int q0 = qt * 64;
    const int t = threadIdx.x, lane = t & 63, w = t >> 6;

    __shared__ __align__(16) u16 Ks[64 * 64];
    __shared__ __align__(16) u16 Vs[64 * 64];
    __shared__ __align__(16) u16 Ps[4][16 * 64];

    // Q fragments: wave w owns q-rows q0 + w*16 .. +15 (held in regs)
    short8 qf[2];
    {
        int qrow = q0 + w * 16 + (lane & 15);
        const u16* qp = Qg + (long long)qrow * (3 * DMODEL) + h * DHEAD + ((lane >> 4) << 3);
        qf[0] = *(const short8*)qp;
        qf[1] = *(const short8*)(qp + 32);
    }

    f32x4 o_acc[4] = {};
    float m_r[4], l_r[4];
#pragma unroll
    for (int r = 0; r < 4; ++r) { m_r[r] = -3.0e38f; l_r[r] = 0.f; }

    const int nt = CAUSAL ? (qt + 1) : (SEQ / 64);

    for (int kt = 0; kt < nt; ++kt) {
        // stage K tile [64k][64d] and V^T tile [64d][64k] (XOR pre-swizzled source)
#pragma unroll
        for (int i = 0; i < 2; ++i) {
            int LL = i * 256 + t;
            int row = LL >> 3, cp = LL & 7, c = cp ^ (row & 7);
            async16(Kg + (long long)(kt * 64 + row) * (3 * DMODEL) + h * DHEAD + (c << 3),
                    &Ks[(i * 256 + w * 64) * 8]);
            async16(VT + (long long)(h * DHEAD + row) * SEQ + kt * 64 + (c << 3),
                    &Vs[(i * 256 + w * 64) * 8]);
        }
        __syncthreads();   // B1: staging complete

        // S = Q K^T  (4 key-frags of 16)
        f32x4 s[4] = {};
#pragma unroll
        for (int kk = 0; kk < 2; ++kk) {
            const int cb = kk * 4 + (lane >> 4);
#pragma unroll
            for (int n = 0; n < 4; ++n) {
                int R = n * 16 + (lane & 15);
                short8 kf = *(const short8*)&Ks[R * 64 + ((cb ^ (R & 7)) << 3)];
                s[n] = __builtin_amdgcn_mfma_f32_16x16x32_bf16(qf[kk], kf, s[n], 0, 0, 0);
            }
        }

        // scale + diagonal causal mask
#pragma unroll
        for (int n = 0; n < 4; ++n) {
            int keyl = n * 16 + (lane & 15);
#pragma unroll
            for (int r = 0; r < 4; ++r) {
                float v = s[n][r] * 0.125f;
                if (CAUSAL && kt == qt) {
                    int ql = w * 16 + ((lane >> 4) << 2) + r;
                    if (keyl > ql) v -= 10000.0f;
                }
                s[n][r] = v;
            }
        }

        // online softmax per q-row (rows: 16 lanes of same (lane>>4) group x reg r)
#pragma unroll
        for (int r = 0; r < 4; ++r) {
            float vm = fmaxf(fmaxf(s[0][r], s[1][r]), fmaxf(s[2][r], s[3][r]));
            vm = fmaxf(vm, __shfl_xor(vm, 1));
            vm = fmaxf(vm, __shfl_xor(vm, 2));
            vm = fmaxf(vm, __shfl_xor(vm, 4));
            vm = fmaxf(vm, __shfl_xor(vm, 8));
            float mn = fmaxf(m_r[r], vm);
            float sf = __expf(m_r[r] - mn);
            m_r[r] = mn;
            float rowsum = 0.f;
#pragma unroll
            for (int n = 0; n < 4; ++n) {
                float p = __expf(s[n][r] - mn);
                s[n][r] = p;
                rowsum += p;
            }
            rowsum += __shfl_xor(rowsum, 1);
            rowsum += __shfl_xor(rowsum, 2);
            rowsum += __shfl_xor(rowsum, 4);
            rowsum += __shfl_xor(rowsum, 8);
            l_r[r] = l_r[r] * sf + rowsum;
#pragma unroll
            for (int d = 0; d < 4; ++d) o_acc[d][r] *= sf;
        }

        // P (C-layout) -> LDS (A-frag layout source), chunk XOR-swizzled
#pragma unroll
        for (int n = 0; n < 4; ++n) {
            int jh = lane & 7;
            int chunk = n * 2 + ((lane & 15) >> 3);
#pragma unroll
            for (int r = 0; r < 4; ++r) {
                int q = ((lane >> 4) << 2) + r;
                Ps[w][q * 64 + ((chunk ^ (q & 7)) << 3) + jh] = f2bf(s[n][r]);
            }
        }
        __syncthreads();   // B2: P visible (and all QK^T reads of Ks done)

        // O += P V  (V^T as B-operand)
#pragma unroll
        for (int kk = 0; kk < 2; ++kk) {
            int q = lane & 15;
            int chunk = (lane >> 4) + kk * 4;
            short8 pf = *(const short8*)&Ps[w][q * 64 + ((chunk ^ (q & 7)) << 3)];
            const int cb = kk * 4 + (lane >> 4);
#pragma unroll
            for (int d = 0; d < 4; ++d) {
                int R = d * 16 + (lane & 15);
                short8 vf = *(const short8*)&Vs[R * 64 + ((cb ^ (R & 7)) << 3)];
                o_acc[d] = __builtin_amdgcn_mfma_f32_16x16x32_bf16(pf, vf, o_acc[d], 0, 0, 0);
            }
        }
        __syncthreads();   // B3: Vs/Ps reads done before next tile staging
    }

    // normalize + write
#pragma unroll
    for (int r = 0; r < 4; ++r) {
        float inv = 1.0f / l_r[r];
        int row = q0 + w * 16 + ((lane >> 4) << 2) + r;
#pragma unroll
        for (int d = 0; d < 4; ++d) {
            int col = h * DHEAD + d * 16 + (lane & 15);
            O[(long long)row * DMODEL + col] = f2bf(o_acc[d][r] * inv);
        }
    }
}

// ---------------------------------------------------------------- f32 row softmax (final)
__global__ __launch_bounds__(256) void softmax_f32(const float* __restrict__ in,
                                                   float* __restrict__ out, int width) {
    const float* row = in + (long long)blockIdx.x * width;
    float* orow = out + (long long)blockIdx.x * width;
    int tid = threadIdx.x;
    __shared__ float red[256];
    int nf4 = width >> 2;
    float4 v = {-1e30f, -1e30f, -1e30f, -1e30f};
    if (tid < nf4) v = ((const float4*)row)[tid];
    float mx = fmaxf(fmaxf(v.x, v.y), fmaxf(v.z, v.w));
    mx = block_max(mx, red);
    float4 e = {0.f, 0.f, 0.f, 0.f};
    float s = 0.f;
    if (tid < nf4) {
        e.x = __expf(v.x - mx); e.y = __expf(v.y - mx);
        e.z = __expf(v.z - mx); e.w = __expf(v.w - mx);
        s = e.x + e.y + e.z + e.w;
    }
    s = block_sum(s, red);
    float inv = 1.0f / s;
    if (tid < nf4) {
        e.x *= inv; e.y *= inv; e.z *= inv; e.w *= inv;
        ((float4*)orow)[tid] = e;
    }
}

// ---------------------------------------------------------------- x = LN(x + fx); emits f32 + bf16
__global__ __launch_bounds__(256) void ln_res_kernel(float* __restrict__ x,
                                                     const float* __restrict__ fx,
                                                     const float* __restrict__ ga,
                                                     const float* __restrict__ gb,
                                                     u16* __restrict__ xb) {
    long long row = blockIdx.x;
    float* xr = x + row * DMODEL;
    const float* fr = fx + row * DMODEL;
    u16* xbr = xb + row * DMODEL;
    int tid = threadIdx.x;
    __shared__ float red[256];

    float4 tv = {0.f, 0.f, 0.f, 0.f};
    if (tid < 192) {
        float4 a = ((const float4*)xr)[tid];
        float4 f = ((const float4*)fr)[tid];
        tv.x = a.x + f.x; tv.y = a.y + f.y; tv.z = a.z + f.z; tv.w = a.w + f.w;
    }
    float sum = tv.x + tv.y + tv.z + tv.w;
    sum = block_sum(sum, red);
    float mean = sum * (1.0f / (float)DMODEL);

    float4 d = {0.f, 0.f, 0.f, 0.f};
    float ss = 0.f;
    if (tid < 192) {
        d.x = tv.x - mean; d.y = tv.y - mean; d.z = tv.z - mean; d.w = tv.w - mean;
        ss = d.x * d.x + d.y * d.y + d.z * d.z + d.w * d.w;
    }
    ss = block_sum(ss, red);
    float stdv = sqrtf(ss / (float)(DMODEL - 1));
    float inv = 1.0f / (stdv + 1e-6f);

    if (tid < 192) {
        float4 A = ((const float4*)ga)[tid];
        float4 B = ((const float4*)gb)[tid];
        float4 o;
        o.x = A.x * d.x * inv + B.x;
        o.y = A.y * d.y * inv + B.y;
        o.z = A.z * d.z * inv + B.z;
        o.w = A.w * d.w * inv + B.w;
        ((float4*)xr)[tid] = o;
        ushort4 ob;
        ob.x = f2bf(o.x); ob.y = f2bf(o.y); ob.z = f2bf(o.z); ob.w = f2bf(o.w);
        ((ushort4*)xbr)[tid] = ob;
    }
}

// ---------------------------------------------------------------- host
struct GArg {
    const u16* A; int lda;
    const void* B; int ldb; int b_f32;
    const float* bias;
    void* C; int ldc; int c_bf16;
    u16* vt; int vt_col0;
    int N, M, K; int relu;
};
static inline void g64(hipStream_t st, const GArg& a) {
    dim3 grid(a.M / 64, a.N / 64);
    hipLaunchKernelGGL((gemm_mfma<64, 64>), grid, dim3(256), 0, st,
                       a.A, a.lda, a.B, a.ldb, a.b_f32, a.bias, a.C, a.ldc, a.c_bf16,
                       a.vt, a.vt_col0, a.K, a.relu);
}
static inline void g128(hipStream_t st, const GArg& a) {
    dim3 grid(a.M / 128, a.N / 128);
    hipLaunchKernelGGL((gemm_mfma<128, 128>), grid, dim3(256), 0, st,
                       a.A, a.lda, a.B, a.ldb, a.b_f32, a.bias, a.C, a.ldc, a.c_bf16,
                       a.vt, a.vt_col0, a.K, a.relu);
}

extern "C" void kernel_launch(void* const* d_in, const int* in_sizes, int n_in,
                              void* d_out, int out_size, void* d_ws, size_t ws_size,
                              hipStream_t stream) {
    const float* xl      = (const float*)d_in[0];
    const float* dl      = (const float*)d_in[1];
    const float* pe      = (const float*)d_in[2];
    const float* enc_wq  = (const float*)d_in[3];
    const float* enc_wk  = (const float*)d_in[4];
    const float* enc_wv  = (const float*)d_in[5];
    const float* enc_wo  = (const float*)d_in[6];
    const float* enc_bo  = (const float*)d_in[7];
    const float* enc_lna = (const float*)d_in[8];
    const float* enc_lnb = (const float*)d_in[9];
    const float* enc_w1  = (const float*)d_in[10];
    const float* enc_b1  = (const float*)d_in[11];
    const float* enc_w2  = (const float*)d_in[12];
    const float* enc_b2  = (const float*)d_in[13];
    const float* dec_wq  = (const float*)d_in[14];
    const float* dec_wk  = (const float*)d_in[15];
    const float* dec_wv  = (const float*)d_in[16];
    const float* dec_wo  = (const float*)d_in[17];
    const float* dec_bo  = (const float*)d_in[18];
    const float* dec_cwq = (const float*)d_in[19];
    const float* dec_cwk = (const float*)d_in[20];
    const float* dec_cwv = (const float*)d_in[21];
    const float* dec_cwo = (const float*)d_in[22];
    const float* dec_cbo = (const float*)d_in[23];
    const float* dec_lna = (const float*)d_in[24];
    const float* dec_lnb = (const float*)d_in[25];
    const float* dec_w1  = (const float*)d_in[26];
    const float* dec_b1  = (const float*)d_in[27];
    const float* dec_w2  = (const float*)d_in[28];
    const float* dec_b2  = (const float*)d_in[29];

    const long long AC   = (long long)SEQ * DMODEL;
    const long long DD   = (long long)DMODEL * DMODEL;
    const long long WH   = (long long)HIDDEN * DMODEL;
    const long long QKVC = (long long)SEQ * 3 * DMODEL;
    const long long SH   = (long long)SEQ * HIDDEN;

    float* mbuf = (float*)d_ws;
    float* xbuf = mbuf + AC;
    float* fbuf = xbuf + AC;
    u16* u = (u16*)(fbuf + AC);
    u16* mb16 = u;  u += AC;
    u16* xb16 = u;  u += AC;
    u16* qkvb = u;  u += QKVC;      // [1024][2304]: q | k | v(unused cols)
    u16* vt   = u;  u += AC;        // V^T [768][1024]
    u16* ob   = u;  u += AC;        // attention out
    u16* hb   = u;  u += SH;        // ffn hidden

    // converted bf16 weights
    u16* W = u;
    long long woff = 0;
    const long long W_ENC_QKV = woff; woff += 18 * DD;
    const long long W_ENC_WO  = woff; woff += 6 * DD;
    const long long W_ENC_W1  = woff; woff += 6 * WH;
    const long long W_ENC_W2  = woff; woff += 6 * WH;
    const long long W_DEC_QKV = woff; woff += 18 * DD;
    const long long W_DEC_CQKV= woff; woff += 18 * DD;
    const long long W_DEC_WO  = woff; woff += 6 * DD;
    const long long W_DEC_CWO = woff; woff += 6 * DD;
    const long long W_DEC_W1  = woff; woff += 6 * WH;
    const long long W_DEC_W2  = woff; woff += 6 * WH;
    const long long need = (long long)((char*)(W + woff) - (char*)d_ws);
    const bool conv = ((long long)ws_size >= need);

    if (conv) {
        auto cvt = [&](const float* src, long long dst_off, long long per, long long sls, long long dls, int L) {
            dim3 grid((unsigned)((per / 4 + 255) / 256), L);
            hipLaunchKernelGGL(cvt_bf16, grid, dim3(256), 0, stream, src, W + dst_off, per, sls, dls);
        };
        cvt(enc_wq, W_ENC_QKV + 0 * DD, DD, DD, 3 * DD, NLAYER);
        cvt(enc_wk, W_ENC_QKV + 1 * DD, DD, DD, 3 * DD, NLAYER);
        cvt(enc_wv, W_ENC_QKV + 2 * DD, DD, DD, 3 * DD, NLAYER);
        cvt(enc_wo, W_ENC_WO, 6 * DD, 0, 0, 1);
        cvt(enc_w1, W_ENC_W1, 6 * WH, 0, 0, 1);
        cvt(enc_w2, W_ENC_W2, 6 * WH, 0, 0, 1);
        cvt(dec_wq, W_DEC_QKV + 0 * DD, DD, DD, 3 * DD, NLAYER);
        cvt(dec_wk, W_DEC_QKV + 1 * DD, DD, DD, 3 * DD, NLAYER);
        cvt(dec_wv, W_DEC_QKV + 2 * DD, DD, DD, 3 * DD, NLAYER);
        cvt(dec_cwq, W_DEC_CQKV + 0 * DD, DD, DD, 3 * DD, NLAYER);
        cvt(dec_cwk, W_DEC_CQKV + 1 * DD, DD, DD, 3 * DD, NLAYER);
        cvt(dec_cwv, W_DEC_CQKV + 2 * DD, DD, DD, 3 * DD, NLAYER);
        cvt(dec_wo, W_DEC_WO, 6 * DD, 0, 0, 1);
        cvt(dec_cwo, W_DEC_CWO, 6 * DD, 0, 0, 1);
        cvt(dec_w1, W_DEC_W1, 6 * WH, 0, 0, 1);
        cvt(dec_w2, W_DEC_W2, 6 * WH, 0, 0, 1);
    }

    hipLaunchKernelGGL(add_pe, dim3((int)(AC / 256)), dim3(256), 0, stream, xl, pe, mbuf, mb16, (int)AC);

    auto attn = [&](int causal) {
        dim3 grid(SEQ / 64, NHEAD);
        if (causal)
            hipLaunchKernelGGL((attn_fused<1>), grid, dim3(256), 0, stream, qkvb, qkvb + DMODEL, vt, ob);
        else
            hipLaunchKernelGGL((attn_fused<0>), grid, dim3(256), 0, stream, qkvb, qkvb + DMODEL, vt, ob);
    };

    // ---------------- encoder ----------------
    for (int l = 0; l < NLAYER; ++l) {
        if (conv) {
            GArg qkv = { mb16, DMODEL, W + W_ENC_QKV + l * 3 * DD, DMODEL, 0, nullptr,
                         qkvb, 3 * DMODEL, 1, vt, 2 * DMODEL, SEQ, 3 * DMODEL, DMODEL, 0 };
            g64(stream, qkv);
        } else {
            const float* wps[3] = { enc_wq + l * DD, enc_wk + l * DD, enc_wv + l * DD };
            for (int j = 0; j < 3; ++j) {
                GArg a = { mb16, DMODEL, wps[j], DMODEL, 1, nullptr,
                           qkvb + j * DMODEL, 3 * DMODEL, 1,
                           (j == 2) ? vt : nullptr, 0, SEQ, DMODEL, DMODEL, 0 };
                g64(stream, a);
            }
        }
        attn(0);
        GArg wo = { ob, DMODEL,
                    conv ? (const void*)(W + W_ENC_WO + l * DD) : (const void*)(enc_wo + l * DD),
                    DMODEL, conv ? 0 : 1, enc_bo + (long long)l * DMODEL,
                    fbuf, DMODEL, 0, nullptr, 0, SEQ, DMODEL, DMODEL, 0 };
        g64(stream, wo);
        hipLaunchKernelGGL(ln_res_kernel, dim3(SEQ), dim3(256), 0, stream,
                           mbuf, fbuf, enc_lna + (long long)(l * 2 + 0) * DMODEL,
                           enc_lnb + (long long)(l * 2 + 0) * DMODEL, mb16);
        GArg f1 = { mb16, DMODEL,
                    conv ? (const void*)(W + W_ENC_W1 + l * WH) : (const void*)(enc_w1 + l * WH),
                    DMODEL, conv ? 0 : 1, enc_b1 + (long long)l * HIDDEN,
                    hb, HIDDEN, 1, nullptr, 0, SEQ, HIDDEN, DMODEL, 1 };
        g128(stream, f1);
        GArg f2 = { hb, HIDDEN,
                    conv ? (const void*)(W + W_ENC_W2 + l * WH) : (const void*)(enc_w2 + l * WH),
                    HIDDEN, conv ? 0 : 1, enc_b2 + (long long)l * DMODEL,
                    fbuf, DMODEL, 0, nullptr, 0, SEQ, DMODEL, HIDDEN, 0 };
        g64(stream, f2);
        hipLaunchKernelGGL(ln_res_kernel, dim3(SEQ), dim3(256), 0, stream,
                           mbuf, fbuf, enc_lna + (long long)(l * 2 + 1) * DMODEL,
                           enc_lnb + (long long)(l * 2 + 1) * DMODEL, mb16);
    }

    hipLaunchKernelGGL(add_pe, dim3((int)(AC / 256)), dim3(256), 0, stream, dl, pe, xbuf, xb16, (int)AC);

    // ---------------- decoder ----------------
    for (int l = 0; l < NLAYER; ++l) {
        // self attention (causal)
        if (conv) {
            GArg qkv = { xb16, DMODEL, W + W_DEC_QKV + l * 3 * DD, DMODEL, 0, nullptr,
                         qkvb, 3 * DMODEL, 1, vt, 2 * DMODEL, SEQ, 3 * DMODEL, DMODEL, 0 };
            g64(stream, qkv);
        } else {
            const float* wps[3] = { dec_wq + l * DD, dec_wk + l * DD, dec_wv + l * DD };
            for (int j = 0; j < 3; ++j) {
                GArg a = { xb16, DMODEL, wps[j], DMODEL, 1, nullptr,
                           qkvb + j * DMODEL, 3 * DMODEL, 1,
                           (j == 2) ? vt : nullptr, 0, SEQ, DMODEL, DMODEL, 0 };
                g64(stream, a);
            }
        }
        attn(1);
        GArg wo = { ob, DMODEL,
                    conv ? (const void*)(W + W_DEC_WO + l * DD) : (const void*)(dec_wo + l * DD),
                    DMODEL, conv ? 0 : 1, dec_bo + (long long)l * DMODEL,
                    fbuf, DMODEL, 0, nullptr, 0, SEQ, DMODEL, DMODEL, 0 };
        g64(stream, wo);
        hipLaunchKernelGGL(ln_res_kernel, dim3(SEQ), dim3(256), 0, stream,
                           xbuf, fbuf, dec_lna + (long long)(l * 3 + 0) * DMODEL,
                           dec_lnb + (long long)(l * 3 + 0) * DMODEL, xb16);

        // cross attention
        if (conv) {
            GArg q = { xb16, DMODEL, W + W_DEC_CQKV + l * 3 * DD, DMODEL, 0, nullptr,
                       qkvb, 3 * DMODEL, 1, nullptr, 0, SEQ, DMODEL, DMODEL, 0 };
            g64(stream, q);
            GArg kv = { mb16, DMODEL, W + W_DEC_CQKV + l * 3 * DD + DD, DMODEL, 0, nullptr,
                        qkvb + DMODEL, 3 * DMODEL, 1, vt, DMODEL, SEQ, 2 * DMODEL, DMODEL, 0 };
            g64(stream, kv);
        } else {
            GArg q = { xb16, DMODEL, dec_cwq + l * DD, DMODEL, 1, nullptr,
                       qkvb, 3 * DMODEL, 1, nullptr, 0, SEQ, DMODEL, DMODEL, 0 };
            g64(stream, q);
            GArg ck = { mb16, DMODEL, dec_cwk + l * DD, DMODEL, 1, nullptr,
                        qkvb + DMODEL, 3 * DMODEL, 1, nullptr, 0, SEQ, DMODEL, DMODEL, 0 };
            g64(stream, ck);
            GArg cv = { mb16, DMODEL, dec_cwv + l * DD, DMODEL, 1, nullptr,
                        qkvb + 2 * DMODEL, 3 * DMODEL, 1, vt, 0, SEQ, DMODEL, DMODEL, 0 };
            g64(stream, cv);
        }
        attn(0);
        GArg cwo = { ob, DMODEL,
                     conv ? (const void*)(W + W_DEC_CWO + l * DD) : (const void*)(dec_cwo + l * DD),
                     DMODEL, conv ? 0 : 1, dec_cbo + (long long)l * DMODEL,
                     fbuf, DMODEL, 0, nullptr, 0, SEQ, DMODEL, DMODEL, 0 };
        g64(stream, cwo);
        hipLaunchKernelGGL(ln_res_kernel, dim3(SEQ), dim3(256), 0, stream,
                           xbuf, fbuf, dec_lna + (long long)(l * 3 + 1) * DMODEL,
                           dec_lnb + (long long)(l * 3 + 1) * DMODEL, xb16);

        // FFN
        GArg f1 = { xb16, DMODEL,
                    conv ? (const void*)(W + W_DEC_W1 + l * WH) : (const void*)(dec_w1 + l * WH),
                    DMODEL, conv ? 0 : 1, dec_b1 + (long long)l * HIDDEN,
                    hb, HIDDEN, 1, nullptr, 0, SEQ, HIDDEN, DMODEL, 1 };
        g128(stream, f1);
        GArg f2 = { hb, HIDDEN,
                    conv ? (const void*)(W + W_DEC_W2 + l * WH) : (const void*)(dec_w2 + l * WH),
                    HIDDEN, conv ? 0 : 1, dec_b2 + (long long)l * DMODEL,
                    fbuf, DMODEL, 0, nullptr, 0, SEQ, DMODEL, HIDDEN, 0 };
        g64(stream, f2);
        hipLaunchKernelGGL(ln_res_kernel, dim3(SEQ), dim3(256), 0, stream,
                           xbuf, fbuf, dec_lna + (long long)(l * 3 + 2) * DMODEL,
                           dec_lnb + (long long)(l * 3 + 2) * DMODEL, xb16);
    }

    hipLaunchKernelGGL(softmax_f32, dim3(SEQ), dim3(256), 0, stream, xbuf, (float*)d_out, DMODEL);
}